// Round 9
// baseline (127.713 us; speedup 1.0000x reference)
//
#include <hip/hip_runtime.h>

#define K_FEATS 256
#define C_FEATS 64
#define RCHUNK 1024
#define RROUNDS (RCHUNK / 64)
#define NDIGIT 1024          // digit = dst>>6, dst<65536 -> digit<1024
#define LCAP 2048            // per-bucket LDS edge capacity (avg 1024)

typedef __attribute__((ext_vector_type(8))) short short8;
typedef __attribute__((ext_vector_type(8))) unsigned short ushort8;
typedef __attribute__((ext_vector_type(4))) float f32x4;

__device__ __forceinline__ unsigned short f2bf(float f) {
    union { float f; unsigned u; } v; v.f = f;
    unsigned r = v.u + 0x7FFF + ((v.u >> 16) & 1);   // RNE, finite inputs
    return (unsigned short)(r >> 16);
}

// ---------------------------------------------------------------------------
// ws layout (bytes) — every GLOBAL buffer is a pure function of the inputs
// (bitwise identical each call => replay-idempotent). nchunk = 782.
//   P1 (uint)        : 0         .. 3,200,000   (dst&63)<<16|src, sorted by dst>>6
//   chunkhist_cm(u32): 3,200,000 .. 6,403,072   [chunk][1024 digits], coalesced
//   chunkhist_dm(u32): 6,403,072 .. 9,606,144   [digit][782 chunks], scanned
//   hwn (bf16)       : 3,200,000 .. 9,600,000   written by gemm AFTER reorder
//                      (lifetime-disjoint with both hists: last hist read =
//                       reorder, which precedes gemm)
//   deg (int)        : 9,606,144 .. 9,806,144
//   off (int)        : 9,806,144 .. 10,006,144  (within-256-block excl scan)
//   bsum (int)       : 10,006,144.. 10,007,168
//   bsum2 (int)      : 10,007,168.. 10,019,968  (3200 ints)
//   wt_g (bf16)      : 10,019,968.. 10,052,736  W^T in bf16
// total ~10.05 MB
// ---------------------------------------------------------------------------

__global__ __launch_bounds__(256) void zero_ints(int* __restrict__ p, int n) {
    int i = blockIdx.x * 256 + threadIdx.x;
    if (i < n) p[i] = 0;
}

// fused: deg histogram + per-chunk 1024-bin digit histogram, CHUNK-MAJOR
// output (each block writes 1024 consecutive dwords -> fully coalesced).
__global__ __launch_bounds__(256) void packhist_kernel(
    const int* __restrict__ dst, int* __restrict__ deg,
    unsigned* __restrict__ chunkhist_cm, int n_edges)
{
    __shared__ unsigned cnt[NDIGIT];
    const int tid = threadIdx.x;
    #pragma unroll
    for (int j = 0; j < NDIGIT / 256; ++j) cnt[tid + j * 256] = 0;
    __syncthreads();
    const int base = blockIdx.x * RCHUNK + tid;
    #pragma unroll
    for (int r = 0; r < RCHUNK / 256; ++r) {
        const int idx = base + r * 256;
        if (idx < n_edges) {
            const int d = dst[idx];
            atomicAdd(&deg[d], 1);
            atomicAdd(&cnt[d >> 6], 1);
        }
    }
    __syncthreads();
    #pragma unroll
    for (int j = 0; j < NDIGIT / 256; ++j) {
        const int dig = tid + j * 256;
        chunkhist_cm[(size_t)blockIdx.x * NDIGIT + dig] = cnt[dig];
    }
}

// LDS-tiled transpose: [nchunk][NDIGIT] -> [NDIGIT][nchunk]. 64x64 tiles,
// padded LDS (65) -> conflict-free; both global sides coalesced.
__global__ __launch_bounds__(256) void transpose_hist_kernel(
    const unsigned* __restrict__ in_cm, unsigned* __restrict__ out_dm, int nchunk)
{
    __shared__ unsigned t[64][65];
    const int tid = threadIdx.x;
    const int tx = tid & 63, ty = tid >> 6;
    const int dig0 = blockIdx.x * 64;
    const int c0   = blockIdx.y * 64;
    #pragma unroll
    for (int j = 0; j < 16; ++j) {
        const int c = c0 + ty + j * 4;
        if (c < nchunk) t[ty + j * 4][tx] = in_cm[(size_t)c * NDIGIT + dig0 + tx];
    }
    __syncthreads();
    const int c = c0 + tx;
    if (c < nchunk) {
        #pragma unroll
        for (int j = 0; j < 16; ++j) {
            const int dig = dig0 + ty + j * 4;
            out_dm[(size_t)dig * nchunk + c] = t[tx][ty + j * 4];
        }
    }
}

// W [k][col] f32  ->  wt [col][k] bf16
__global__ __launch_bounds__(256) void transpose_w_kernel(
    const float* __restrict__ w, unsigned short* __restrict__ wt)
{
    const int e2 = blockIdx.x * 1024 + threadIdx.x;
    #pragma unroll
    for (int j = 0; j < 4; ++j) {
        const int idx = e2 + j * 256;
        const int col = idx >> 8, k = idx & 255;
        wt[idx] = f2bf(w[k * C_FEATS + col]);
    }
}

// ---------------------------------------------------------------------------
// MFMA projection (validated): hwn[n][c] = bf16(norm[n]*(h@W)[n][c])
// ---------------------------------------------------------------------------
__global__ __launch_bounds__(256) void gemm_mfma_kernel(
    const float* __restrict__ h, const unsigned short* __restrict__ wt_g,
    const float* __restrict__ norm, unsigned short* __restrict__ hwn, int n_nodes)
{
    __shared__ __align__(16) unsigned char lds[65536];

    const int tid  = threadIdx.x;
    const int row0 = blockIdx.x * 64;

    #pragma unroll
    for (int j = 0; j < 8; ++j) {
        const int ch = j * 256 + tid;
        const int r = ch >> 5, k0 = (ch & 31) * 8;
        const int row = row0 + r;
        ushort8 v;
        if (row < n_nodes) {
            const float4 f0 = *reinterpret_cast<const float4*>(h + (size_t)row * K_FEATS + k0);
            const float4 f1 = *reinterpret_cast<const float4*>(h + (size_t)row * K_FEATS + k0 + 4);
            v[0]=f2bf(f0.x); v[1]=f2bf(f0.y); v[2]=f2bf(f0.z); v[3]=f2bf(f0.w);
            v[4]=f2bf(f1.x); v[5]=f2bf(f1.y); v[6]=f2bf(f1.z); v[7]=f2bf(f1.w);
        } else {
            v = (ushort8)0;
        }
        const int addr = (r * 512 + k0 * 2) ^ ((r & 7) << 4);
        *reinterpret_cast<ushort8*>(lds + addr) = v;
    }
    #pragma unroll
    for (int j = 0; j < 8; ++j) {
        const int ch = j * 256 + tid;
        const int col = ch >> 5, k0 = (ch & 31) * 8;
        const ushort8 v = *reinterpret_cast<const ushort8*>(wt_g + ch * 8);
        const int addr = 32768 + ((col * 512 + k0 * 2) ^ ((col & 7) << 4));
        *reinterpret_cast<ushort8*>(lds + addr) = v;
    }
    __syncthreads();

    const int lane = tid & 63, w = tid >> 6;
    const int r16 = lane & 15, kg = lane >> 4;
    const int x = (r16 & 7) << 4;

    f32x4 acc[4];
    #pragma unroll
    for (int n = 0; n < 4; ++n) acc[n] = (f32x4)0.f;

    #pragma unroll
    for (int kb = 0; kb < 8; ++kb) {
        const int common = (r16 * 512 + kb * 64 + kg * 16) ^ x;
        const short8 a = *reinterpret_cast<const short8*>(lds + w * 8192 + common);
        #pragma unroll
        for (int n = 0; n < 4; ++n) {
            const short8 b = *reinterpret_cast<const short8*>(lds + 32768 + n * 8192 + common);
            acc[n] = __builtin_amdgcn_mfma_f32_16x16x32_bf16(a, b, acc[n], 0, 0, 0);
        }
    }

    #pragma unroll
    for (int i = 0; i < 4; ++i) {
        const int row = row0 + w * 16 + kg * 4 + i;
        if (row < n_nodes) {
            const float nv = norm[row];
            #pragma unroll
            for (int n = 0; n < 4; ++n) {
                hwn[(size_t)row * C_FEATS + n * 16 + r16] = f2bf(acc[n][i] * nv);
            }
        }
    }
}

// ---------------------------------------------------------------------------
// generic scan pieces; scan_block supports in==out (reads before writes)
// ---------------------------------------------------------------------------
__global__ __launch_bounds__(256) void scan_block_kernel(
    const int* in, int* out, int* bsum, int n)
{
    __shared__ int s[256];
    const int tid = threadIdx.x;
    const int i = blockIdx.x * 256 + tid;
    const int v = (i < n) ? in[i] : 0;
    s[tid] = v;
    __syncthreads();
    #pragma unroll
    for (int d = 1; d < 256; d <<= 1) {
        int t = (tid >= d) ? s[tid - d] : 0;
        __syncthreads();
        s[tid] += t;
        __syncthreads();
    }
    if (i < n) out[i] = s[tid] - v;
    if (tid == 255) bsum[blockIdx.x] = s[255];
}

// exclusive scan of up to 4096 block sums (16 per thread)
__global__ __launch_bounds__(256) void scan_partials_kernel(int* __restrict__ bsum, int nb)
{
    __shared__ int s[256];
    const int tid = threadIdx.x;
    int v[16];
    int sum = 0;
    #pragma unroll
    for (int j = 0; j < 16; ++j) {
        const int i = tid * 16 + j;
        v[j] = (i < nb) ? bsum[i] : 0;
        sum += v[j];
    }
    s[tid] = sum;
    __syncthreads();
    #pragma unroll
    for (int d = 1; d < 256; d <<= 1) {
        int t = (tid >= d) ? s[tid - d] : 0;
        __syncthreads();
        s[tid] += t;
        __syncthreads();
    }
    int base = s[tid] - sum;
    #pragma unroll
    for (int j = 0; j < 16; ++j) {
        const int i = tid * 16 + j;
        if (i < nb) { bsum[i] = base; base += v[j]; }
    }
}

// ---------------------------------------------------------------------------
// Single-pass deterministic stable radix scatter by digit = dst>>6 (10 bits).
// One wave per 1024-edge chunk; stable ranks via 11-bit ballot match
// (bit 10 = invalid sentinel). Reads src/dst directly; writes
// P1 = (dst&63)<<16 | src. slot = scanned chunkhist + bsum2 (scan_add fused).
// ---------------------------------------------------------------------------
__global__ __launch_bounds__(64) void rreorder_pass(
    const int* __restrict__ src, const int* __restrict__ dst,
    unsigned* __restrict__ P1, const unsigned* __restrict__ choff,
    const int* __restrict__ bsum2, int n_edges, int nchunk)
{
    __shared__ unsigned cnt[NDIGIT];
    const int c = blockIdx.x;
    const int lane = threadIdx.x;
    #pragma unroll
    for (int j = 0; j < NDIGIT / 64; ++j) cnt[lane + j * 64] = 0;
    __syncthreads();
    const int base = c * RCHUNK;

    unsigned dA = 0, sA = 0, dB = 0, sB = 0;
    if (base + lane < n_edges)      { dA = dst[base + lane];      sA = src[base + lane]; }
    if (base + 64 + lane < n_edges) { dB = dst[base + 64 + lane]; sB = src[base + 64 + lane]; }

    for (int r = 0; r < RROUNDS; ++r) {
        unsigned dC = 0, sC = 0;
        const int idxC = base + (r + 2) * 64 + lane;
        if (r + 2 < RROUNDS && idxC < n_edges) { dC = dst[idxC]; sC = src[idxC]; }

        const int idx = base + r * 64 + lane;
        const bool valid = idx < n_edges;
        const int g = valid ? (int)(dA >> 6) : NDIGIT;
        unsigned long long m = ~0ull;
        #pragma unroll
        for (int b = 0; b < 11; ++b) {
            const unsigned long long bb = __ballot((g >> b) & 1);
            m &= ((g >> b) & 1) ? bb : ~bb;
        }
        const unsigned long long below = m & ((1ull << lane) - 1ull);
        const int laneRank = __popcll(below);
        const int total = __popcll(m);
        const bool isFirst = (below == 0ull);
        unsigned oldc = 0;
        if (valid) oldc = cnt[g];
        __syncthreads();
        if (valid) {
            const int gi = g * nchunk + c;
            const unsigned slot = choff[gi] + (unsigned)bsum2[gi >> 8]
                                + oldc + (unsigned)laneRank;
            P1[slot] = ((dA & 63u) << 16) | sA;
            if (isFirst) cnt[g] = oldc + (unsigned)total;
        }
        __syncthreads();
        dA = dB; sA = sB; dB = dC; sB = sC;
    }
}

// ---------------------------------------------------------------------------
// Aggregate + finalize. Block = 64-node bucket (digit group), 512 threads.
// LDS cursor-scatter bucket edges into per-node lists, then wave-per-node
// 4-edge-parallel uint2 gather, shfl reduce, fused norm/bias/relu store.
// ---------------------------------------------------------------------------
__global__ __launch_bounds__(512) void aggregate_kernel(
    const uint2* __restrict__ hwn2, const unsigned* __restrict__ P1,
    const int* __restrict__ off, const int* __restrict__ bsum,
    const float* __restrict__ norm, const float* __restrict__ bias,
    float* __restrict__ out, int n_nodes, int n_edges)
{
    __shared__ int cum[65];
    __shared__ int cur[64];
    __shared__ unsigned short lsrc[LCAP];

    const int tid = threadIdx.x;
    const int n0 = blockIdx.x * 64;

    if (tid < 65) {
        const int n = n0 + tid;
        cum[tid] = (n < n_nodes) ? (off[n] + bsum[n >> 8]) : n_edges;
    }
    __syncthreads();
    const int s = cum[0];
    const int bucketsz = cum[64] - s;
    if (tid < 64) cur[tid] = cum[tid] - s;
    __syncthreads();

    const int lane = tid & 63;
    const int wv = tid >> 6;           // 8 waves
    const int q  = lane >> 4;          // edge slot 0..3
    const int c4 = lane & 15;          // uint2 index within 128B row

    if (bucketsz <= LCAP) {
        for (int i = tid; i < bucketsz; i += 512) {
            const unsigned key = P1[s + i];
            const int pos = atomicAdd(&cur[key >> 16], 1);
            lsrc[pos] = (unsigned short)key;
        }
        __syncthreads();
        for (int nn = wv; nn < 64; nn += 8) {
            const int node = n0 + nn;
            if (node >= n_nodes) break;
            const int ls = cum[nn] - s;
            const int le = cum[nn + 1] - s;
            float a0 = 0.f, a1 = 0.f, a2 = 0.f, a3 = 0.f;
            int e = ls + q;
            for (; e + 4 < le; e += 8) {
                const uint2 u = hwn2[(size_t)lsrc[e] * 16 + c4];
                const uint2 v = hwn2[(size_t)lsrc[e + 4] * 16 + c4];
                a0 += __uint_as_float(u.x << 16) + __uint_as_float(v.x << 16);
                a1 += __uint_as_float(u.x & 0xFFFF0000u) + __uint_as_float(v.x & 0xFFFF0000u);
                a2 += __uint_as_float(u.y << 16) + __uint_as_float(v.y << 16);
                a3 += __uint_as_float(u.y & 0xFFFF0000u) + __uint_as_float(v.y & 0xFFFF0000u);
            }
            for (; e < le; e += 4) {
                const uint2 u = hwn2[(size_t)lsrc[e] * 16 + c4];
                a0 += __uint_as_float(u.x << 16);
                a1 += __uint_as_float(u.x & 0xFFFF0000u);
                a2 += __uint_as_float(u.y << 16);
                a3 += __uint_as_float(u.y & 0xFFFF0000u);
            }
            a0 += __shfl_xor(a0, 16); a1 += __shfl_xor(a1, 16);
            a2 += __shfl_xor(a2, 16); a3 += __shfl_xor(a3, 16);
            a0 += __shfl_xor(a0, 32); a1 += __shfl_xor(a1, 32);
            a2 += __shfl_xor(a2, 32); a3 += __shfl_xor(a3, 32);
            if (q == 0) {
                const float nv = norm[node];
                const float4 bv = *reinterpret_cast<const float4*>(bias + c4 * 4);
                float4 o;
                o.x = fmaxf(fmaf(a0, nv, bv.x), 0.f);
                o.y = fmaxf(fmaf(a1, nv, bv.y), 0.f);
                o.z = fmaxf(fmaf(a2, nv, bv.z), 0.f);
                o.w = fmaxf(fmaf(a3, nv, bv.w), 0.f);
                *reinterpret_cast<float4*>(out + (size_t)node * C_FEATS + c4 * 4) = o;
            }
        }
    } else {
        // safe fallback for oversized buckets (never expected on this input)
        for (int nn = wv; nn < 64; nn += 8) {
            const int node = n0 + nn;
            if (node >= n_nodes) break;
            float a0 = 0.f, a1 = 0.f, a2 = 0.f, a3 = 0.f;
            for (int i = q; i < bucketsz; i += 4) {
                const unsigned key = P1[s + i];
                if ((int)(key >> 16) == nn) {
                    const uint2 u = hwn2[(size_t)(key & 0xFFFFu) * 16 + c4];
                    a0 += __uint_as_float(u.x << 16);
                    a1 += __uint_as_float(u.x & 0xFFFF0000u);
                    a2 += __uint_as_float(u.y << 16);
                    a3 += __uint_as_float(u.y & 0xFFFF0000u);
                }
            }
            a0 += __shfl_xor(a0, 16); a1 += __shfl_xor(a1, 16);
            a2 += __shfl_xor(a2, 16); a3 += __shfl_xor(a3, 16);
            a0 += __shfl_xor(a0, 32); a1 += __shfl_xor(a1, 32);
            a2 += __shfl_xor(a2, 32); a3 += __shfl_xor(a3, 32);
            if (q == 0) {
                const float nv = norm[node];
                const float4 bv = *reinterpret_cast<const float4*>(bias + c4 * 4);
                float4 o;
                o.x = fmaxf(fmaf(a0, nv, bv.x), 0.f);
                o.y = fmaxf(fmaf(a1, nv, bv.y), 0.f);
                o.z = fmaxf(fmaf(a2, nv, bv.z), 0.f);
                o.w = fmaxf(fmaf(a3, nv, bv.w), 0.f);
                *reinterpret_cast<float4*>(out + (size_t)node * C_FEATS + c4 * 4) = o;
            }
        }
    }
}

extern "C" void kernel_launch(void* const* d_in, const int* in_sizes, int n_in,
                              void* d_out, int out_size, void* d_ws, size_t ws_size,
                              hipStream_t stream) {
    const float* h      = (const float*)d_in[0];
    const float* norm   = (const float*)d_in[1];
    const int*   src    = (const int*)d_in[2];
    const int*   dst    = (const int*)d_in[3];
    const float* weight = (const float*)d_in[4];
    const float* bias   = (const float*)d_in[5];

    const int n_nodes = in_sizes[1];
    const int n_edges = in_sizes[2];

    char* ws = (char*)d_ws;
    unsigned* P1            = (unsigned*)(ws + 0);
    unsigned* chunkhist_cm  = (unsigned*)(ws + 3200000);
    unsigned* chunkhist_dm  = (unsigned*)(ws + 6403072);
    unsigned short* hwn     = (unsigned short*)(ws + 3200000);   // after reorder
    int* deg                = (int*)(ws + 9606144);
    int* off                = (int*)(ws + 9806144);
    int* bsum               = (int*)(ws + 10006144);
    int* bsum2              = (int*)(ws + 10007168);
    unsigned short* wt_g    = (unsigned short*)(ws + 10019968);

    const int nb_scan = (n_nodes + 255) / 256;                    // 196
    const int nchunk  = (n_edges + RCHUNK - 1) / RCHUNK;          // 782
    const int nscan   = NDIGIT * nchunk;                          // 800768
    const int nb_r    = (nscan + 255) / 256;                      // 3128 <= 4096
    const int ngroup  = (n_nodes + 63) / 64;                      // 782

    // deg zero + fused deg/digit histograms (chunk-major, coalesced)
    zero_ints<<<(n_nodes + 255) / 256, 256, 0, stream>>>(deg, n_nodes);
    packhist_kernel<<<nchunk, 256, 0, stream>>>(dst, deg, chunkhist_cm, n_edges);

    // transpose to digit-major
    {
        dim3 g(NDIGIT / 64, (nchunk + 63) / 64);
        transpose_hist_kernel<<<g, 256, 0, stream>>>(chunkhist_cm, chunkhist_dm, nchunk);
    }

    // cumdeg pieces (off within-block scan + scanned bsum; add fused downstream)
    scan_block_kernel<<<nb_scan, 256, 0, stream>>>(deg, off, bsum, n_nodes);
    scan_partials_kernel<<<1, 256, 0, stream>>>(bsum, nb_scan);

    // digit-major scan of chunkhist (in-place) + partials
    scan_block_kernel<<<nb_r, 256, 0, stream>>>((int*)chunkhist_dm, (int*)chunkhist_dm, bsum2, nscan);
    scan_partials_kernel<<<1, 256, 0, stream>>>(bsum2, nb_r);

    // single-pass stable scatter by dst>>6
    rreorder_pass<<<nchunk, 64, 0, stream>>>(src, dst, P1, chunkhist_dm, bsum2, n_edges, nchunk);

    // projection (hwn overwrites hist regions after their last read)
    transpose_w_kernel<<<16, 256, 0, stream>>>(weight, wt_g);
    gemm_mfma_kernel<<<(n_nodes + 63) / 64, 256, 0, stream>>>(h, wt_g, norm, hwn, n_nodes);

    // bucket-local split + gather-aggregate + finalize
    aggregate_kernel<<<ngroup, 512, 0, stream>>>(
        (const uint2*)hwn, P1, off, bsum, norm, bias, (float*)d_out, n_nodes, n_edges);
}

// Round 10
// 84.998 us; speedup vs baseline: 1.5025x; 1.5025x over previous
//
#include <hip/hip_runtime.h>

#define K_FEATS 256
#define C_FEATS 64
#define RCHUNK 1024
#define RROUNDS (RCHUNK / 64)
#define NDIGIT 1024          // digit = dst>>6, dst<65536 -> digit<1024
#define LCAP 2048            // per-bucket LDS edge capacity (avg ~1024)

typedef __attribute__((ext_vector_type(8))) short short8;
typedef __attribute__((ext_vector_type(8))) unsigned short ushort8;
typedef __attribute__((ext_vector_type(4))) float f32x4;

__device__ __forceinline__ unsigned short f2bf(float f) {
    union { float f; unsigned u; } v; v.f = f;
    unsigned r = v.u + 0x7FFF + ((v.u >> 16) & 1);   // RNE, finite inputs
    return (unsigned short)(r >> 16);
}

// ---------------------------------------------------------------------------
// ws layout (bytes) — every GLOBAL buffer is a pure function of the inputs
// (bitwise identical each call => replay-idempotent). nchunk = 782.
//   P1 (uint)        : 0         .. 3,200,000   (dst&63)<<16|src, sorted by dst>>6
//   chunkhist_cm(u32): 3,200,000 .. 6,403,072   [chunk][1024 digits] coalesced
//   chunkhist_dm(u32): 6,403,072 .. 9,606,144   [digit][782 chunks], scanned
//   hwn (bf16)       : 3,200,000 .. 9,600,000   written by gemm AFTER reorder
//                      (cm dead after transpose, dm dead after reorder)
//   bsum2 (int)      : 9,606,144 .. 9,618,656   (3128 ints)
//   digbase (int)    : 9,618,656 .. 9,622,760   (1025 ints)
//   wt_g (bf16)      : 9,622,784 .. 9,655,552   W^T in bf16 (16B aligned)
// total ~9.66 MB. No deg/off/bsum buffers anymore.
// ---------------------------------------------------------------------------

// per-chunk 1024-bin digit histogram, CHUNK-MAJOR coalesced output.
// No global deg atomics. uint4-vectorized dst read (1 uint4/thread).
__global__ __launch_bounds__(256) void packhist_kernel(
    const int* __restrict__ dst, unsigned* __restrict__ chunkhist_cm, int n_edges)
{
    __shared__ unsigned cnt[NDIGIT];
    const int tid = threadIdx.x;
    #pragma unroll
    for (int j = 0; j < NDIGIT / 256; ++j) cnt[tid + j * 256] = 0;
    __syncthreads();
    const int e0 = blockIdx.x * RCHUNK + tid * 4;
    if (e0 + 3 < n_edges) {
        const int4 d4 = *reinterpret_cast<const int4*>(dst + e0);
        atomicAdd(&cnt[d4.x >> 6], 1);
        atomicAdd(&cnt[d4.y >> 6], 1);
        atomicAdd(&cnt[d4.z >> 6], 1);
        atomicAdd(&cnt[d4.w >> 6], 1);
    } else {
        #pragma unroll
        for (int j = 0; j < 4; ++j) {
            if (e0 + j < n_edges) atomicAdd(&cnt[dst[e0 + j] >> 6], 1);
        }
    }
    __syncthreads();
    // 4 consecutive dwords per thread -> uint4 coalesced store
    uint4 o;
    o.x = cnt[tid * 4 + 0]; o.y = cnt[tid * 4 + 1];
    o.z = cnt[tid * 4 + 2]; o.w = cnt[tid * 4 + 3];
    *reinterpret_cast<uint4*>(&chunkhist_cm[(size_t)blockIdx.x * NDIGIT + tid * 4]) = o;
}

// LDS-tiled transpose: [nchunk][NDIGIT] -> [NDIGIT][nchunk]. 64x64 tiles.
__global__ __launch_bounds__(256) void transpose_hist_kernel(
    const unsigned* __restrict__ in_cm, unsigned* __restrict__ out_dm, int nchunk)
{
    __shared__ unsigned t[64][65];
    const int tid = threadIdx.x;
    const int tx = tid & 63, ty = tid >> 6;
    const int dig0 = blockIdx.x * 64;
    const int c0   = blockIdx.y * 64;
    #pragma unroll
    for (int j = 0; j < 16; ++j) {
        const int c = c0 + ty + j * 4;
        if (c < nchunk) t[ty + j * 4][tx] = in_cm[(size_t)c * NDIGIT + dig0 + tx];
    }
    __syncthreads();
    const int c = c0 + tx;
    if (c < nchunk) {
        #pragma unroll
        for (int j = 0; j < 16; ++j) {
            const int dig = dig0 + ty + j * 4;
            out_dm[(size_t)dig * nchunk + c] = t[tx][ty + j * 4];
        }
    }
}

// generic scan pieces; scan_block supports in==out (reads before writes)
__global__ __launch_bounds__(256) void scan_block_kernel(
    const int* in, int* out, int* bsum, int n)
{
    __shared__ int s[256];
    const int tid = threadIdx.x;
    const int i = blockIdx.x * 256 + tid;
    const int v = (i < n) ? in[i] : 0;
    s[tid] = v;
    __syncthreads();
    #pragma unroll
    for (int d = 1; d < 256; d <<= 1) {
        int t = (tid >= d) ? s[tid - d] : 0;
        __syncthreads();
        s[tid] += t;
        __syncthreads();
    }
    if (i < n) out[i] = s[tid] - v;
    if (tid == 255) bsum[blockIdx.x] = s[255];
}

// exclusive scan of up to 4096 block sums (16 per thread)
__global__ __launch_bounds__(256) void scan_partials_kernel(int* __restrict__ bsum, int nb)
{
    __shared__ int s[256];
    const int tid = threadIdx.x;
    int v[16];
    int sum = 0;
    #pragma unroll
    for (int j = 0; j < 16; ++j) {
        const int i = tid * 16 + j;
        v[j] = (i < nb) ? bsum[i] : 0;
        sum += v[j];
    }
    s[tid] = sum;
    __syncthreads();
    #pragma unroll
    for (int d = 1; d < 256; d <<= 1) {
        int t = (tid >= d) ? s[tid - d] : 0;
        __syncthreads();
        s[tid] += t;
        __syncthreads();
    }
    int base = s[tid] - sum;
    #pragma unroll
    for (int j = 0; j < 16; ++j) {
        const int i = tid * 16 + j;
        if (i < nb) { bsum[i] = base; base += v[j]; }
    }
}

// fused: W transpose to bf16 + digbase snapshot (digit bucket bases) so the
// aggregate can run after hwn overwrites the scanned histogram region.
__global__ __launch_bounds__(256) void transpose_w_digbase_kernel(
    const float* __restrict__ w, unsigned short* __restrict__ wt,
    const unsigned* __restrict__ choff, const int* __restrict__ bsum2,
    int* __restrict__ digbase, int n_edges, int nchunk)
{
    const int gid = blockIdx.x * 256 + threadIdx.x;
    if (gid < NDIGIT) {
        const int gi = gid * nchunk;
        digbase[gid] = (int)choff[gi] + bsum2[gi >> 8];
    }
    if (gid == 0) digbase[NDIGIT] = n_edges;

    const int e2 = gid * 4;
    #pragma unroll
    for (int j = 0; j < 4; ++j) {
        const int idx = e2 + j;                 // linear in wt [col][k]
        const int col = idx >> 8, k = idx & 255;
        wt[idx] = f2bf(w[k * C_FEATS + col]);
    }
}

// ---------------------------------------------------------------------------
// MFMA projection (validated): hwn[n][c] = bf16(norm[n]*(h@W)[n][c])
// ---------------------------------------------------------------------------
__global__ __launch_bounds__(256) void gemm_mfma_kernel(
    const float* __restrict__ h, const unsigned short* __restrict__ wt_g,
    const float* __restrict__ norm, unsigned short* __restrict__ hwn, int n_nodes)
{
    __shared__ __align__(16) unsigned char lds[65536];

    const int tid  = threadIdx.x;
    const int row0 = blockIdx.x * 64;

    #pragma unroll
    for (int j = 0; j < 8; ++j) {
        const int ch = j * 256 + tid;
        const int r = ch >> 5, k0 = (ch & 31) * 8;
        const int row = row0 + r;
        ushort8 v;
        if (row < n_nodes) {
            const float4 f0 = *reinterpret_cast<const float4*>(h + (size_t)row * K_FEATS + k0);
            const float4 f1 = *reinterpret_cast<const float4*>(h + (size_t)row * K_FEATS + k0 + 4);
            v[0]=f2bf(f0.x); v[1]=f2bf(f0.y); v[2]=f2bf(f0.z); v[3]=f2bf(f0.w);
            v[4]=f2bf(f1.x); v[5]=f2bf(f1.y); v[6]=f2bf(f1.z); v[7]=f2bf(f1.w);
        } else {
            v = (ushort8)0;
        }
        const int addr = (r * 512 + k0 * 2) ^ ((r & 7) << 4);
        *reinterpret_cast<ushort8*>(lds + addr) = v;
    }
    #pragma unroll
    for (int j = 0; j < 8; ++j) {
        const int ch = j * 256 + tid;
        const int col = ch >> 5, k0 = (ch & 31) * 8;
        const ushort8 v = *reinterpret_cast<const ushort8*>(wt_g + ch * 8);
        const int addr = 32768 + ((col * 512 + k0 * 2) ^ ((col & 7) << 4));
        *reinterpret_cast<ushort8*>(lds + addr) = v;
    }
    __syncthreads();

    const int lane = tid & 63, w = tid >> 6;
    const int r16 = lane & 15, kg = lane >> 4;
    const int x = (r16 & 7) << 4;

    f32x4 acc[4];
    #pragma unroll
    for (int n = 0; n < 4; ++n) acc[n] = (f32x4)0.f;

    #pragma unroll
    for (int kb = 0; kb < 8; ++kb) {
        const int common = (r16 * 512 + kb * 64 + kg * 16) ^ x;
        const short8 a = *reinterpret_cast<const short8*>(lds + w * 8192 + common);
        #pragma unroll
        for (int n = 0; n < 4; ++n) {
            const short8 b = *reinterpret_cast<const short8*>(lds + 32768 + n * 8192 + common);
            acc[n] = __builtin_amdgcn_mfma_f32_16x16x32_bf16(a, b, acc[n], 0, 0, 0);
        }
    }

    #pragma unroll
    for (int i = 0; i < 4; ++i) {
        const int row = row0 + w * 16 + kg * 4 + i;
        if (row < n_nodes) {
            const float nv = norm[row];
            #pragma unroll
            for (int n = 0; n < 4; ++n) {
                hwn[(size_t)row * C_FEATS + n * 16 + r16] = f2bf(acc[n][i] * nv);
            }
        }
    }
}

// ---------------------------------------------------------------------------
// Single-pass deterministic stable radix scatter by digit = dst>>6 (10 bits).
// (validated rounds 8-9)
// ---------------------------------------------------------------------------
__global__ __launch_bounds__(64) void rreorder_pass(
    const int* __restrict__ src, const int* __restrict__ dst,
    unsigned* __restrict__ P1, const unsigned* __restrict__ choff,
    const int* __restrict__ bsum2, int n_edges, int nchunk)
{
    __shared__ unsigned cnt[NDIGIT];
    const int c = blockIdx.x;
    const int lane = threadIdx.x;
    #pragma unroll
    for (int j = 0; j < NDIGIT / 64; ++j) cnt[lane + j * 64] = 0;
    __syncthreads();
    const int base = c * RCHUNK;

    unsigned dA = 0, sA = 0, dB = 0, sB = 0;
    if (base + lane < n_edges)      { dA = dst[base + lane];      sA = src[base + lane]; }
    if (base + 64 + lane < n_edges) { dB = dst[base + 64 + lane]; sB = src[base + 64 + lane]; }

    for (int r = 0; r < RROUNDS; ++r) {
        unsigned dC = 0, sC = 0;
        const int idxC = base + (r + 2) * 64 + lane;
        if (r + 2 < RROUNDS && idxC < n_edges) { dC = dst[idxC]; sC = src[idxC]; }

        const int idx = base + r * 64 + lane;
        const bool valid = idx < n_edges;
        const int g = valid ? (int)(dA >> 6) : NDIGIT;
        unsigned long long m = ~0ull;
        #pragma unroll
        for (int b = 0; b < 11; ++b) {
            const unsigned long long bb = __ballot((g >> b) & 1);
            m &= ((g >> b) & 1) ? bb : ~bb;
        }
        const unsigned long long below = m & ((1ull << lane) - 1ull);
        const int laneRank = __popcll(below);
        const int total = __popcll(m);
        const bool isFirst = (below == 0ull);
        unsigned oldc = 0;
        if (valid) oldc = cnt[g];
        __syncthreads();
        if (valid) {
            const int gi = g * nchunk + c;
            const unsigned slot = choff[gi] + (unsigned)bsum2[gi >> 8]
                                + oldc + (unsigned)laneRank;
            P1[slot] = ((dA & 63u) << 16) | sA;
            if (isFirst) cnt[g] = oldc + (unsigned)total;
        }
        __syncthreads();
        dA = dB; sA = sB; dB = dC; sB = sC;
    }
}

// ---------------------------------------------------------------------------
// Aggregate + finalize. Block = 64-node bucket, 512 threads. Bucket bounds
// from digbase; per-node segments built locally: LDS count -> 64-lane shfl
// prefix scan -> cursor scatter (LDS->LDS, keys staged). Then wave-per-node
// 4-edge-parallel uint2 gather, shfl reduce, fused norm/bias/relu store.
// ---------------------------------------------------------------------------
__global__ __launch_bounds__(512) void aggregate_kernel(
    const uint2* __restrict__ hwn2, const unsigned* __restrict__ P1,
    const int* __restrict__ digbase,
    const float* __restrict__ norm, const float* __restrict__ bias,
    float* __restrict__ out, int n_nodes)
{
    __shared__ unsigned stage[LCAP];
    __shared__ unsigned short lsrc[LCAP];
    __shared__ int cnt64[64];
    __shared__ int cur64[64];
    __shared__ int segbase[65];

    const int tid = threadIdx.x;
    const int b = blockIdx.x;
    const int n0 = b * 64;

    const int s = digbase[b];
    const int bucketsz = digbase[b + 1] - s;

    if (tid < 64) { cnt64[tid] = 0; cur64[tid] = 0; }
    __syncthreads();

    const int lane = tid & 63;
    const int wv = tid >> 6;           // 8 waves
    const int q  = lane >> 4;          // edge slot 0..3
    const int c4 = lane & 15;          // uint2 index within 128B row

    if (bucketsz <= LCAP) {
        // pass 1: stage keys + per-node counts
        for (int i = tid; i < bucketsz; i += 512) {
            const unsigned key = P1[s + i];
            stage[i] = key;
            atomicAdd(&cnt64[key >> 16], 1);
        }
        __syncthreads();
        // 64-lane exclusive prefix scan (wave 0)
        if (tid < 64) {
            int x = cnt64[tid];
            #pragma unroll
            for (int d = 1; d < 64; d <<= 1) {
                const int t = __shfl_up(x, d);
                if (tid >= d) x += t;
            }
            segbase[tid + 1] = x;      // inclusive
            if (tid == 0) segbase[0] = 0;
        }
        __syncthreads();
        // pass 2: cursor scatter into per-node lists
        for (int i = tid; i < bucketsz; i += 512) {
            const unsigned key = stage[i];
            const int nn = key >> 16;
            const int pos = atomicAdd(&cur64[nn], 1);
            lsrc[segbase[nn] + pos] = (unsigned short)key;
        }
        __syncthreads();
        // gather
        for (int nn = wv; nn < 64; nn += 8) {
            const int node = n0 + nn;
            if (node >= n_nodes) break;
            const int ls = segbase[nn];
            const int le = segbase[nn + 1];
            float a0 = 0.f, a1 = 0.f, a2 = 0.f, a3 = 0.f;
            int e = ls + q;
            for (; e + 4 < le; e += 8) {
                const uint2 u = hwn2[(size_t)lsrc[e] * 16 + c4];
                const uint2 v = hwn2[(size_t)lsrc[e + 4] * 16 + c4];
                a0 += __uint_as_float(u.x << 16) + __uint_as_float(v.x << 16);
                a1 += __uint_as_float(u.x & 0xFFFF0000u) + __uint_as_float(v.x & 0xFFFF0000u);
                a2 += __uint_as_float(u.y << 16) + __uint_as_float(v.y << 16);
                a3 += __uint_as_float(u.y & 0xFFFF0000u) + __uint_as_float(v.y & 0xFFFF0000u);
            }
            for (; e < le; e += 4) {
                const uint2 u = hwn2[(size_t)lsrc[e] * 16 + c4];
                a0 += __uint_as_float(u.x << 16);
                a1 += __uint_as_float(u.x & 0xFFFF0000u);
                a2 += __uint_as_float(u.y << 16);
                a3 += __uint_as_float(u.y & 0xFFFF0000u);
            }
            a0 += __shfl_xor(a0, 16); a1 += __shfl_xor(a1, 16);
            a2 += __shfl_xor(a2, 16); a3 += __shfl_xor(a3, 16);
            a0 += __shfl_xor(a0, 32); a1 += __shfl_xor(a1, 32);
            a2 += __shfl_xor(a2, 32); a3 += __shfl_xor(a3, 32);
            if (q == 0) {
                const float nv = norm[node];
                const float4 bv = *reinterpret_cast<const float4*>(bias + c4 * 4);
                float4 o;
                o.x = fmaxf(fmaf(a0, nv, bv.x), 0.f);
                o.y = fmaxf(fmaf(a1, nv, bv.y), 0.f);
                o.z = fmaxf(fmaf(a2, nv, bv.z), 0.f);
                o.w = fmaxf(fmaf(a3, nv, bv.w), 0.f);
                *reinterpret_cast<float4*>(out + (size_t)node * C_FEATS + c4 * 4) = o;
            }
        }
    } else {
        // safe fallback for oversized buckets (never expected on this input)
        for (int nn = wv; nn < 64; nn += 8) {
            const int node = n0 + nn;
            if (node >= n_nodes) break;
            float a0 = 0.f, a1 = 0.f, a2 = 0.f, a3 = 0.f;
            for (int i = q; i < bucketsz; i += 4) {
                const unsigned key = P1[s + i];
                if ((int)(key >> 16) == nn) {
                    const uint2 u = hwn2[(size_t)(key & 0xFFFFu) * 16 + c4];
                    a0 += __uint_as_float(u.x << 16);
                    a1 += __uint_as_float(u.x & 0xFFFF0000u);
                    a2 += __uint_as_float(u.y << 16);
                    a3 += __uint_as_float(u.y & 0xFFFF0000u);
                }
            }
            a0 += __shfl_xor(a0, 16); a1 += __shfl_xor(a1, 16);
            a2 += __shfl_xor(a2, 16); a3 += __shfl_xor(a3, 16);
            a0 += __shfl_xor(a0, 32); a1 += __shfl_xor(a1, 32);
            a2 += __shfl_xor(a2, 32); a3 += __shfl_xor(a3, 32);
            if (q == 0) {
                const float nv = norm[node];
                const float4 bv = *reinterpret_cast<const float4*>(bias + c4 * 4);
                float4 o;
                o.x = fmaxf(fmaf(a0, nv, bv.x), 0.f);
                o.y = fmaxf(fmaf(a1, nv, bv.y), 0.f);
                o.z = fmaxf(fmaf(a2, nv, bv.z), 0.f);
                o.w = fmaxf(fmaf(a3, nv, bv.w), 0.f);
                *reinterpret_cast<float4*>(out + (size_t)node * C_FEATS + c4 * 4) = o;
            }
        }
    }
}

extern "C" void kernel_launch(void* const* d_in, const int* in_sizes, int n_in,
                              void* d_out, int out_size, void* d_ws, size_t ws_size,
                              hipStream_t stream) {
    const float* h      = (const float*)d_in[0];
    const float* norm   = (const float*)d_in[1];
    const int*   src    = (const int*)d_in[2];
    const int*   dst    = (const int*)d_in[3];
    const float* weight = (const float*)d_in[4];
    const float* bias   = (const float*)d_in[5];

    const int n_nodes = in_sizes[1];
    const int n_edges = in_sizes[2];

    char* ws = (char*)d_ws;
    unsigned* P1            = (unsigned*)(ws + 0);
    unsigned* chunkhist_cm  = (unsigned*)(ws + 3200000);
    unsigned* chunkhist_dm  = (unsigned*)(ws + 6403072);
    unsigned short* hwn     = (unsigned short*)(ws + 3200000);   // after reorder
    int* bsum2              = (int*)(ws + 9606144);
    int* digbase            = (int*)(ws + 9618656);
    unsigned short* wt_g    = (unsigned short*)(ws + 9622784);

    const int nchunk  = (n_edges + RCHUNK - 1) / RCHUNK;          // 782
    const int nscan   = NDIGIT * nchunk;                          // 800768
    const int nb_r    = (nscan + 255) / 256;                      // 3128 <= 4096
    const int ngroup  = (n_nodes + 63) / 64;                      // 782

    // 1) per-chunk digit histogram (chunk-major, coalesced, no global atomics)
    packhist_kernel<<<nchunk, 256, 0, stream>>>(dst, chunkhist_cm, n_edges);

    // 2) transpose to digit-major
    {
        dim3 g(NDIGIT / 64, (nchunk + 63) / 64);
        transpose_hist_kernel<<<g, 256, 0, stream>>>(chunkhist_cm, chunkhist_dm, nchunk);
    }

    // 3-4) digit-major scan of chunkhist (in-place) + partials
    scan_block_kernel<<<nb_r, 256, 0, stream>>>((int*)chunkhist_dm, (int*)chunkhist_dm, bsum2, nscan);
    scan_partials_kernel<<<1, 256, 0, stream>>>(bsum2, nb_r);

    // 5) W transpose + digit-base snapshot (needs scanned hist)
    transpose_w_digbase_kernel<<<16, 256, 0, stream>>>(
        weight, wt_g, chunkhist_dm, bsum2, digbase, n_edges, nchunk);

    // 6) single-pass stable scatter by dst>>6
    rreorder_pass<<<nchunk, 64, 0, stream>>>(src, dst, P1, chunkhist_dm, bsum2, n_edges, nchunk);

    // 7) projection (hwn overwrites hist regions after their last read)
    gemm_mfma_kernel<<<(n_nodes + 63) / 64, 256, 0, stream>>>(h, wt_g, norm, hwn, n_nodes);

    // 8) bucket-local split + gather-aggregate + finalize
    aggregate_kernel<<<ngroup, 512, 0, stream>>>(
        (const uint2*)hwn, P1, digbase, norm, bias, (float*)d_out, n_nodes);
}

// Round 11
// 84.173 us; speedup vs baseline: 1.5173x; 1.0098x over previous
//
#include <hip/hip_runtime.h>

#define K_FEATS 256
#define C_FEATS 64
#define RCHUNK 1024
#define RROUNDS (RCHUNK / 64)
#define NDIGIT 512           // digit = dst>>7, dst<65536 -> digit<512
#define DSHIFT 7
#define NMASK 127            // node-in-bucket mask (128 nodes per bucket)
#define LCAP 2560            // per-bucket LDS edge capacity (avg 2048, +11 sigma)

typedef __attribute__((ext_vector_type(8))) short short8;
typedef __attribute__((ext_vector_type(8))) unsigned short ushort8;
typedef __attribute__((ext_vector_type(4))) float f32x4;

__device__ __forceinline__ unsigned short f2bf(float f) {
    union { float f; unsigned u; } v; v.f = f;
    unsigned r = v.u + 0x7FFF + ((v.u >> 16) & 1);   // RNE, finite inputs
    return (unsigned short)(r >> 16);
}

__device__ __forceinline__ float bflo(unsigned u) { return __uint_as_float(u << 16); }
__device__ __forceinline__ float bfhi(unsigned u) { return __uint_as_float(u & 0xFFFF0000u); }

// ---------------------------------------------------------------------------
// ws layout (bytes) — every GLOBAL buffer is a pure function of the inputs
// (bitwise identical each call => replay-idempotent). nchunk = 782.
//   P1 (uint)        : 0         .. 3,200,000   (dst&127)<<16|src, sorted by dst>>7
//   chunkhist_cm(u32): 3,200,000 .. 4,801,536   [chunk][512 digits] coalesced
//   chunkhist_dm(u32): 4,801,536 .. 6,403,072   [digit][782 chunks], scanned
//   hwn (bf16)       : 3,200,000 .. 9,600,000   written by gemm AFTER reorder
//                      (cm dead after scan, dm dead after reorder)
//   bsum2 (int)      : 9,606,144 .. 9,612,400   (1564 ints)
//   digbase (int)    : 9,618,656 .. 9,620,708   (513 ints)
//   wt_g (bf16)      : 9,622,784 .. 9,655,552   W^T in bf16 (16B aligned)
// total ~9.66 MB
// ---------------------------------------------------------------------------

// per-chunk 512-bin digit histogram, CHUNK-MAJOR coalesced output.
__global__ __launch_bounds__(256) void packhist_kernel(
    const int* __restrict__ dst, unsigned* __restrict__ chunkhist_cm, int n_edges)
{
    __shared__ unsigned cnt[NDIGIT];
    const int tid = threadIdx.x;
    #pragma unroll
    for (int j = 0; j < NDIGIT / 256; ++j) cnt[tid + j * 256] = 0;
    __syncthreads();
    const int e0 = blockIdx.x * RCHUNK + tid * 4;
    if (e0 + 3 < n_edges) {
        const int4 d4 = *reinterpret_cast<const int4*>(dst + e0);
        atomicAdd(&cnt[d4.x >> DSHIFT], 1);
        atomicAdd(&cnt[d4.y >> DSHIFT], 1);
        atomicAdd(&cnt[d4.z >> DSHIFT], 1);
        atomicAdd(&cnt[d4.w >> DSHIFT], 1);
    } else {
        #pragma unroll
        for (int j = 0; j < 4; ++j) {
            if (e0 + j < n_edges) atomicAdd(&cnt[dst[e0 + j] >> DSHIFT], 1);
        }
    }
    __syncthreads();
    uint2 o;
    o.x = cnt[tid * 2 + 0]; o.y = cnt[tid * 2 + 1];
    *reinterpret_cast<uint2*>(&chunkhist_cm[(size_t)blockIdx.x * NDIGIT + tid * 2]) = o;
}

// scan over dm-ordering while READING cm with transposed indexing
// (fuses the former transpose kernel; strided 4B reads are L3-benign).
__global__ __launch_bounds__(256) void scan_block_t_kernel(
    const unsigned* __restrict__ in_cm, int* __restrict__ out_dm,
    int* __restrict__ bsum, int n, int nchunk)
{
    __shared__ int s[256];
    const int tid = threadIdx.x;
    const int i = blockIdx.x * 256 + tid;      // flat digit-major index
    int v = 0;
    if (i < n) {
        const int dig = i / nchunk;
        const int c   = i - dig * nchunk;
        v = (int)in_cm[(size_t)c * NDIGIT + dig];
    }
    s[tid] = v;
    __syncthreads();
    #pragma unroll
    for (int d = 1; d < 256; d <<= 1) {
        int t = (tid >= d) ? s[tid - d] : 0;
        __syncthreads();
        s[tid] += t;
        __syncthreads();
    }
    if (i < n) out_dm[i] = s[tid] - v;
    if (tid == 255) bsum[blockIdx.x] = s[255];
}

// exclusive scan of up to 4096 block sums (16 per thread)
__global__ __launch_bounds__(256) void scan_partials_kernel(int* __restrict__ bsum, int nb)
{
    __shared__ int s[256];
    const int tid = threadIdx.x;
    int v[16];
    int sum = 0;
    #pragma unroll
    for (int j = 0; j < 16; ++j) {
        const int i = tid * 16 + j;
        v[j] = (i < nb) ? bsum[i] : 0;
        sum += v[j];
    }
    s[tid] = sum;
    __syncthreads();
    #pragma unroll
    for (int d = 1; d < 256; d <<= 1) {
        int t = (tid >= d) ? s[tid - d] : 0;
        __syncthreads();
        s[tid] += t;
        __syncthreads();
    }
    int base = s[tid] - sum;
    #pragma unroll
    for (int j = 0; j < 16; ++j) {
        const int i = tid * 16 + j;
        if (i < nb) { bsum[i] = base; base += v[j]; }
    }
}

// fused: W transpose to bf16 + digbase snapshot (digit bucket bases)
__global__ __launch_bounds__(256) void transpose_w_digbase_kernel(
    const float* __restrict__ w, unsigned short* __restrict__ wt,
    const unsigned* __restrict__ choff, const int* __restrict__ bsum2,
    int* __restrict__ digbase, int n_edges, int nchunk)
{
    const int gid = blockIdx.x * 256 + threadIdx.x;
    if (gid < NDIGIT) {
        const int gi = gid * nchunk;
        digbase[gid] = (int)choff[gi] + bsum2[gi >> 8];
    }
    if (gid == 0) digbase[NDIGIT] = n_edges;

    const int e2 = gid * 4;
    #pragma unroll
    for (int j = 0; j < 4; ++j) {
        const int idx = e2 + j;                 // linear in wt [col][k]
        const int col = idx >> 8, k = idx & 255;
        wt[idx] = f2bf(w[k * C_FEATS + col]);
    }
}

// ---------------------------------------------------------------------------
// MFMA projection (validated): hwn[n][c] = bf16(norm[n]*(h@W)[n][c])
// ---------------------------------------------------------------------------
__global__ __launch_bounds__(256) void gemm_mfma_kernel(
    const float* __restrict__ h, const unsigned short* __restrict__ wt_g,
    const float* __restrict__ norm, unsigned short* __restrict__ hwn, int n_nodes)
{
    __shared__ __align__(16) unsigned char lds[65536];

    const int tid  = threadIdx.x;
    const int row0 = blockIdx.x * 64;

    #pragma unroll
    for (int j = 0; j < 8; ++j) {
        const int ch = j * 256 + tid;
        const int r = ch >> 5, k0 = (ch & 31) * 8;
        const int row = row0 + r;
        ushort8 v;
        if (row < n_nodes) {
            const float4 f0 = *reinterpret_cast<const float4*>(h + (size_t)row * K_FEATS + k0);
            const float4 f1 = *reinterpret_cast<const float4*>(h + (size_t)row * K_FEATS + k0 + 4);
            v[0]=f2bf(f0.x); v[1]=f2bf(f0.y); v[2]=f2bf(f0.z); v[3]=f2bf(f0.w);
            v[4]=f2bf(f1.x); v[5]=f2bf(f1.y); v[6]=f2bf(f1.z); v[7]=f2bf(f1.w);
        } else {
            v = (ushort8)0;
        }
        const int addr = (r * 512 + k0 * 2) ^ ((r & 7) << 4);
        *reinterpret_cast<ushort8*>(lds + addr) = v;
    }
    #pragma unroll
    for (int j = 0; j < 8; ++j) {
        const int ch = j * 256 + tid;
        const int col = ch >> 5, k0 = (ch & 31) * 8;
        const ushort8 v = *reinterpret_cast<const ushort8*>(wt_g + ch * 8);
        const int addr = 32768 + ((col * 512 + k0 * 2) ^ ((col & 7) << 4));
        *reinterpret_cast<ushort8*>(lds + addr) = v;
    }
    __syncthreads();

    const int lane = tid & 63, w = tid >> 6;
    const int r16 = lane & 15, kg = lane >> 4;
    const int x = (r16 & 7) << 4;

    f32x4 acc[4];
    #pragma unroll
    for (int n = 0; n < 4; ++n) acc[n] = (f32x4)0.f;

    #pragma unroll
    for (int kb = 0; kb < 8; ++kb) {
        const int common = (r16 * 512 + kb * 64 + kg * 16) ^ x;
        const short8 a = *reinterpret_cast<const short8*>(lds + w * 8192 + common);
        #pragma unroll
        for (int n = 0; n < 4; ++n) {
            const short8 b = *reinterpret_cast<const short8*>(lds + 32768 + n * 8192 + common);
            acc[n] = __builtin_amdgcn_mfma_f32_16x16x32_bf16(a, b, acc[n], 0, 0, 0);
        }
    }

    #pragma unroll
    for (int i = 0; i < 4; ++i) {
        const int row = row0 + w * 16 + kg * 4 + i;
        if (row < n_nodes) {
            const float nv = norm[row];
            #pragma unroll
            for (int n = 0; n < 4; ++n) {
                hwn[(size_t)row * C_FEATS + n * 16 + r16] = f2bf(acc[n][i] * nv);
            }
        }
    }
}

// ---------------------------------------------------------------------------
// Single-pass deterministic stable radix scatter by digit = dst>>7 (9 bits).
// One wave per 1024-edge chunk; stable ranks via 10-bit ballot match
// (value 512 = invalid sentinel). Writes P1 = (dst&127)<<16 | src.
// ---------------------------------------------------------------------------
__global__ __launch_bounds__(64) void rreorder_pass(
    const int* __restrict__ src, const int* __restrict__ dst,
    unsigned* __restrict__ P1, const unsigned* __restrict__ choff,
    const int* __restrict__ bsum2, int n_edges, int nchunk)
{
    __shared__ unsigned cnt[NDIGIT];
    const int c = blockIdx.x;
    const int lane = threadIdx.x;
    #pragma unroll
    for (int j = 0; j < NDIGIT / 64; ++j) cnt[lane + j * 64] = 0;
    __syncthreads();
    const int base = c * RCHUNK;

    unsigned dA = 0, sA = 0, dB = 0, sB = 0;
    if (base + lane < n_edges)      { dA = dst[base + lane];      sA = src[base + lane]; }
    if (base + 64 + lane < n_edges) { dB = dst[base + 64 + lane]; sB = src[base + 64 + lane]; }

    for (int r = 0; r < RROUNDS; ++r) {
        unsigned dC = 0, sC = 0;
        const int idxC = base + (r + 2) * 64 + lane;
        if (r + 2 < RROUNDS && idxC < n_edges) { dC = dst[idxC]; sC = src[idxC]; }

        const int idx = base + r * 64 + lane;
        const bool valid = idx < n_edges;
        const int g = valid ? (int)(dA >> DSHIFT) : NDIGIT;
        unsigned long long m = ~0ull;
        #pragma unroll
        for (int b = 0; b < 10; ++b) {
            const unsigned long long bb = __ballot((g >> b) & 1);
            m &= ((g >> b) & 1) ? bb : ~bb;
        }
        const unsigned long long below = m & ((1ull << lane) - 1ull);
        const int laneRank = __popcll(below);
        const int total = __popcll(m);
        const bool isFirst = (below == 0ull);
        unsigned oldc = 0;
        if (valid) oldc = cnt[g];
        __syncthreads();
        if (valid) {
            const int gi = g * nchunk + c;
            const unsigned slot = choff[gi] + (unsigned)bsum2[gi >> 8]
                                + oldc + (unsigned)laneRank;
            P1[slot] = ((dA & (unsigned)NMASK) << 16) | sA;
            if (isFirst) cnt[g] = oldc + (unsigned)total;
        }
        __syncthreads();
        dA = dB; sA = sB; dB = dC; sB = sC;
    }
}

// ---------------------------------------------------------------------------
// Aggregate + finalize. Block = 128-node bucket, 512 threads. Per-node
// segments built locally (LDS count -> paired shfl scan -> cursor scatter).
// Gather: 8 lanes per 128B row (uint4), 8 edges in parallel, unroll 2;
// shfl_xor(8,16,32) reduce; fused norm/bias/relu 2x float4 store.
// ---------------------------------------------------------------------------
__global__ __launch_bounds__(512) void aggregate_kernel(
    const uint4* __restrict__ hwn4, const unsigned* __restrict__ P1,
    const int* __restrict__ digbase,
    const float* __restrict__ norm, const float* __restrict__ bias,
    float* __restrict__ out, int n_nodes)
{
    __shared__ unsigned stage[LCAP];
    __shared__ unsigned short lsrc[LCAP];
    __shared__ int cnt128[128];
    __shared__ int cur128[128];
    __shared__ int segbase[129];

    const int tid = threadIdx.x;
    const int b = blockIdx.x;
    const int n0 = b * 128;

    const int s = digbase[b];
    const int bucketsz = digbase[b + 1] - s;

    if (tid < 128) { cnt128[tid] = 0; cur128[tid] = 0; }
    __syncthreads();

    const int lane = tid & 63;
    const int wv = tid >> 6;           // 8 waves
    const int q  = lane >> 3;          // edge slot 0..7
    const int c8 = lane & 7;           // uint4 index within 128B row

    if (bucketsz <= LCAP) {
        // pass 1: stage keys + per-node counts
        for (int i = tid; i < bucketsz; i += 512) {
            const unsigned key = P1[s + i];
            stage[i] = key;
            atomicAdd(&cnt128[key >> 16], 1);
        }
        __syncthreads();
        // 128-element exclusive scan: wave 0, 2 elements per lane
        if (tid < 64) {
            const int a = cnt128[2 * tid], bb = cnt128[2 * tid + 1];
            int p = a + bb;
            #pragma unroll
            for (int d = 1; d < 64; d <<= 1) {
                const int t = __shfl_up(p, d);
                if (tid >= d) p += t;
            }
            segbase[2 * tid]     = p - a - bb;
            segbase[2 * tid + 1] = p - bb;
            if (tid == 63) segbase[128] = p;
        }
        __syncthreads();
        // pass 2: cursor scatter into per-node lists
        for (int i = tid; i < bucketsz; i += 512) {
            const unsigned key = stage[i];
            const int nn = key >> 16;
            const int pos = atomicAdd(&cur128[nn], 1);
            lsrc[segbase[nn] + pos] = (unsigned short)key;
        }
        __syncthreads();
        // gather
        for (int nn = wv; nn < 128; nn += 8) {
            const int node = n0 + nn;
            if (node >= n_nodes) break;
            const int ls = segbase[nn];
            const int le = segbase[nn + 1];
            float a0=0.f,a1=0.f,a2=0.f,a3=0.f,a4=0.f,a5=0.f,a6=0.f,a7=0.f;
            int e = ls + q;
            for (; e + 8 < le; e += 16) {
                const uint4 u = hwn4[(size_t)lsrc[e] * 8 + c8];
                const uint4 v = hwn4[(size_t)lsrc[e + 8] * 8 + c8];
                a0 += bflo(u.x) + bflo(v.x); a1 += bfhi(u.x) + bfhi(v.x);
                a2 += bflo(u.y) + bflo(v.y); a3 += bfhi(u.y) + bfhi(v.y);
                a4 += bflo(u.z) + bflo(v.z); a5 += bfhi(u.z) + bfhi(v.z);
                a6 += bflo(u.w) + bflo(v.w); a7 += bfhi(u.w) + bfhi(v.w);
            }
            for (; e < le; e += 8) {
                const uint4 u = hwn4[(size_t)lsrc[e] * 8 + c8];
                a0 += bflo(u.x); a1 += bfhi(u.x);
                a2 += bflo(u.y); a3 += bfhi(u.y);
                a4 += bflo(u.z); a5 += bfhi(u.z);
                a6 += bflo(u.w); a7 += bfhi(u.w);
            }
            #pragma unroll
            for (int d = 8; d < 64; d <<= 1) {
                a0 += __shfl_xor(a0, d); a1 += __shfl_xor(a1, d);
                a2 += __shfl_xor(a2, d); a3 += __shfl_xor(a3, d);
                a4 += __shfl_xor(a4, d); a5 += __shfl_xor(a5, d);
                a6 += __shfl_xor(a6, d); a7 += __shfl_xor(a7, d);
            }
            if (q == 0) {
                const float nv = norm[node];
                const float4 b0 = *reinterpret_cast<const float4*>(bias + c8 * 8);
                const float4 b1 = *reinterpret_cast<const float4*>(bias + c8 * 8 + 4);
                float4 o0, o1;
                o0.x = fmaxf(fmaf(a0, nv, b0.x), 0.f);
                o0.y = fmaxf(fmaf(a1, nv, b0.y), 0.f);
                o0.z = fmaxf(fmaf(a2, nv, b0.z), 0.f);
                o0.w = fmaxf(fmaf(a3, nv, b0.w), 0.f);
                o1.x = fmaxf(fmaf(a4, nv, b1.x), 0.f);
                o1.y = fmaxf(fmaf(a5, nv, b1.y), 0.f);
                o1.z = fmaxf(fmaf(a6, nv, b1.z), 0.f);
                o1.w = fmaxf(fmaf(a7, nv, b1.w), 0.f);
                float* po = out + (size_t)node * C_FEATS + c8 * 8;
                *reinterpret_cast<float4*>(po)     = o0;
                *reinterpret_cast<float4*>(po + 4) = o1;
            }
        }
    } else {
        // safe fallback for oversized buckets (never expected on this input)
        for (int nn = wv; nn < 128; nn += 8) {
            const int node = n0 + nn;
            if (node >= n_nodes) break;
            float a0=0.f,a1=0.f,a2=0.f,a3=0.f,a4=0.f,a5=0.f,a6=0.f,a7=0.f;
            for (int i = q; i < bucketsz; i += 8) {
                const unsigned key = P1[s + i];
                if ((int)(key >> 16) == nn) {
                    const uint4 u = hwn4[(size_t)(key & 0xFFFFu) * 8 + c8];
                    a0 += bflo(u.x); a1 += bfhi(u.x);
                    a2 += bflo(u.y); a3 += bfhi(u.y);
                    a4 += bflo(u.z); a5 += bfhi(u.z);
                    a6 += bflo(u.w); a7 += bfhi(u.w);
                }
            }
            #pragma unroll
            for (int d = 8; d < 64; d <<= 1) {
                a0 += __shfl_xor(a0, d); a1 += __shfl_xor(a1, d);
                a2 += __shfl_xor(a2, d); a3 += __shfl_xor(a3, d);
                a4 += __shfl_xor(a4, d); a5 += __shfl_xor(a5, d);
                a6 += __shfl_xor(a6, d); a7 += __shfl_xor(a7, d);
            }
            if (q == 0) {
                const float nv = norm[node];
                const float4 b0 = *reinterpret_cast<const float4*>(bias + c8 * 8);
                const float4 b1 = *reinterpret_cast<const float4*>(bias + c8 * 8 + 4);
                float4 o0, o1;
                o0.x = fmaxf(fmaf(a0, nv, b0.x), 0.f);
                o0.y = fmaxf(fmaf(a1, nv, b0.y), 0.f);
                o0.z = fmaxf(fmaf(a2, nv, b0.z), 0.f);
                o0.w = fmaxf(fmaf(a3, nv, b0.w), 0.f);
                o1.x = fmaxf(fmaf(a4, nv, b1.x), 0.f);
                o1.y = fmaxf(fmaf(a5, nv, b1.y), 0.f);
                o1.z = fmaxf(fmaf(a6, nv, b1.z), 0.f);
                o1.w = fmaxf(fmaf(a7, nv, b1.w), 0.f);
                float* po = out + (size_t)node * C_FEATS + c8 * 8;
                *reinterpret_cast<float4*>(po)     = o0;
                *reinterpret_cast<float4*>(po + 4) = o1;
            }
        }
    }
}

extern "C" void kernel_launch(void* const* d_in, const int* in_sizes, int n_in,
                              void* d_out, int out_size, void* d_ws, size_t ws_size,
                              hipStream_t stream) {
    const float* h      = (const float*)d_in[0];
    const float* norm   = (const float*)d_in[1];
    const int*   src    = (const int*)d_in[2];
    const int*   dst    = (const int*)d_in[3];
    const float* weight = (const float*)d_in[4];
    const float* bias   = (const float*)d_in[5];

    const int n_nodes = in_sizes[1];
    const int n_edges = in_sizes[2];

    char* ws = (char*)d_ws;
    unsigned* P1            = (unsigned*)(ws + 0);
    unsigned* chunkhist_cm  = (unsigned*)(ws + 3200000);
    unsigned* chunkhist_dm  = (unsigned*)(ws + 4801536);
    unsigned short* hwn     = (unsigned short*)(ws + 3200000);   // after reorder
    int* bsum2              = (int*)(ws + 9606144);
    int* digbase            = (int*)(ws + 9618656);
    unsigned short* wt_g    = (unsigned short*)(ws + 9622784);

    const int nchunk  = (n_edges + RCHUNK - 1) / RCHUNK;          // 782
    const int nscan   = NDIGIT * nchunk;                          // 400384
    const int nb_r    = (nscan + 255) / 256;                      // 1564 <= 4096
    const int ngroup  = (n_nodes + 127) / 128;                    // 391

    // 1) per-chunk digit histogram (chunk-major, coalesced)
    packhist_kernel<<<nchunk, 256, 0, stream>>>(dst, chunkhist_cm, n_edges);

    // 2-3) digit-major scan (reads cm transposed, writes dm) + partials
    scan_block_t_kernel<<<nb_r, 256, 0, stream>>>(chunkhist_cm, (int*)chunkhist_dm,
                                                  bsum2, nscan, nchunk);
    scan_partials_kernel<<<1, 256, 0, stream>>>(bsum2, nb_r);

    // 4) W transpose + digit-base snapshot (needs scanned hist)
    transpose_w_digbase_kernel<<<16, 256, 0, stream>>>(
        weight, wt_g, chunkhist_dm, bsum2, digbase, n_edges, nchunk);

    // 5) single-pass stable scatter by dst>>7
    rreorder_pass<<<nchunk, 64, 0, stream>>>(src, dst, P1, chunkhist_dm, bsum2, n_edges, nchunk);

    // 6) projection (hwn overwrites hist regions after their last read)
    gemm_mfma_kernel<<<(n_nodes + 63) / 64, 256, 0, stream>>>(h, wt_g, norm, hwn, n_nodes);

    // 7) bucket-local split + gather-aggregate + finalize
    aggregate_kernel<<<ngroup, 512, 0, stream>>>(
        (const uint4*)hwn, P1, digbase, norm, bias, (float*)d_out, n_nodes);
}

// Round 12
// 73.507 us; speedup vs baseline: 1.7374x; 1.1451x over previous
//
#include <hip/hip_runtime.h>

#define K_FEATS 256
#define C_FEATS 64
#define RCHUNK 1024
#define RROUNDS (RCHUNK / 64)
#define NDIGIT 512           // digit = dst>>7, dst<65536 -> digit<512
#define DSHIFT 7
#define NMASK 127
#define LCAP 2560            // per-bucket LDS edge capacity (avg 2048)

typedef __attribute__((ext_vector_type(8))) short short8;
typedef __attribute__((ext_vector_type(8))) unsigned short ushort8;
typedef __attribute__((ext_vector_type(4))) float f32x4;

__device__ __forceinline__ unsigned short f2bf(float f) {
    union { float f; unsigned u; } v; v.f = f;
    unsigned r = v.u + 0x7FFF + ((v.u >> 16) & 1);   // RNE, finite inputs
    return (unsigned short)(r >> 16);
}

__device__ __forceinline__ float bflo(unsigned u) { return __uint_as_float(u << 16); }
__device__ __forceinline__ float bfhi(unsigned u) { return __uint_as_float(u & 0xFFFF0000u); }

// ---------------------------------------------------------------------------
// ws layout (bytes) — every GLOBAL buffer is a pure function of the inputs.
// nchunk = 782. hwn is de-aliased from the histograms so gemm can run
// CONCURRENTLY with reorder (block-range fusion).
//   P1 (uint)   : 0          ..  3,200,000   (dst&127)<<16|src, sorted by dst>>7
//   dm (u32)    : 3,200,000  ..  4,801,536   [digit][782 chunks], scanned
//   cm (u16)    : 4,801,536  ..  5,602,304   [chunk][512 digits] coalesced
//   hwn (bf16)  : 5,602,304  .. 12,002,304
//   bsum2 (int) : 12,002,304 .. 12,008,560   (1564 ints)
//   digbase(int): 12,008,560 .. 12,010,612   (513 ints)
//   wt_g (bf16) : 12,010,624 .. 12,043,392
// total ~12.05 MB (round 1 proved ws >= 12.8 MB)
// ---------------------------------------------------------------------------

// fused: per-chunk 512-bin digit histogram (u16 chunk-major, coalesced)
// [blocks 0..nchunk) + W transpose to bf16 [blocks nchunk..nchunk+16)
__global__ __launch_bounds__(256) void packhist_w_kernel(
    const int* __restrict__ dst, unsigned short* __restrict__ cm16,
    const float* __restrict__ w, unsigned short* __restrict__ wt,
    int n_edges, int nchunk)
{
    const int tid = threadIdx.x;
    if ((int)blockIdx.x < nchunk) {
        __shared__ unsigned cnt[NDIGIT];
        #pragma unroll
        for (int j = 0; j < NDIGIT / 256; ++j) cnt[tid + j * 256] = 0;
        __syncthreads();
        const int e0 = blockIdx.x * RCHUNK + tid * 4;
        if (e0 + 3 < n_edges) {
            const int4 d4 = *reinterpret_cast<const int4*>(dst + e0);
            atomicAdd(&cnt[d4.x >> DSHIFT], 1);
            atomicAdd(&cnt[d4.y >> DSHIFT], 1);
            atomicAdd(&cnt[d4.z >> DSHIFT], 1);
            atomicAdd(&cnt[d4.w >> DSHIFT], 1);
        } else {
            #pragma unroll
            for (int j = 0; j < 4; ++j) {
                if (e0 + j < n_edges) atomicAdd(&cnt[dst[e0 + j] >> DSHIFT], 1);
            }
        }
        __syncthreads();
        const unsigned o = cnt[tid * 2] | (cnt[tid * 2 + 1] << 16);
        reinterpret_cast<unsigned*>(cm16)[(size_t)blockIdx.x * (NDIGIT / 2) + tid] = o;
    } else {
        const int e2 = ((int)blockIdx.x - nchunk) * 1024 + tid;
        #pragma unroll
        for (int j = 0; j < 4; ++j) {
            const int idx = e2 + j * 256;           // linear in wt [col][k]
            const int col = idx >> 8, k = idx & 255;
            wt[idx] = f2bf(w[k * C_FEATS + col]);
        }
    }
}

// block-local exclusive scan over digit-major ordering, reading cm16 with
// transposed indexing (strided u16 reads, L3-benign).
__global__ __launch_bounds__(256) void scan_block_t_kernel(
    const unsigned short* __restrict__ cm16, int* __restrict__ out_dm,
    int* __restrict__ bsum, int n, int nchunk)
{
    __shared__ int s[256];
    const int tid = threadIdx.x;
    const int i = blockIdx.x * 256 + tid;      // flat digit-major index
    int v = 0;
    if (i < n) {
        const int dig = i / nchunk;
        const int c   = i - dig * nchunk;
        v = (int)cm16[(size_t)c * NDIGIT + dig];
    }
    s[tid] = v;
    __syncthreads();
    #pragma unroll
    for (int d = 1; d < 256; d <<= 1) {
        int t = (tid >= d) ? s[tid - d] : 0;
        __syncthreads();
        s[tid] += t;
        __syncthreads();
    }
    if (i < n) out_dm[i] = s[tid] - v;
    if (tid == 255) bsum[blockIdx.x] = s[255];
}

// exclusive scan of block sums (16/thread, nb<=4096) + digbase snapshot
__global__ __launch_bounds__(256) void scan_partials_digbase_kernel(
    int* __restrict__ bsum, int nb, const int* __restrict__ dm,
    int* __restrict__ digbase, int n_edges, int nchunk)
{
    __shared__ int s[256];
    const int tid = threadIdx.x;
    int v[16];
    int sum = 0;
    #pragma unroll
    for (int j = 0; j < 16; ++j) {
        const int i = tid * 16 + j;
        v[j] = (i < nb) ? bsum[i] : 0;
        sum += v[j];
    }
    s[tid] = sum;
    __syncthreads();
    #pragma unroll
    for (int d = 1; d < 256; d <<= 1) {
        int t = (tid >= d) ? s[tid - d] : 0;
        __syncthreads();
        s[tid] += t;
        __syncthreads();
    }
    int base = s[tid] - sum;
    #pragma unroll
    for (int j = 0; j < 16; ++j) {
        const int i = tid * 16 + j;
        if (i < nb) { bsum[i] = base; base += v[j]; }
    }
    __syncthreads();   // bsum stores drained (vmcnt(0) before barrier)
    for (int g = tid; g < NDIGIT; g += 256) {
        const int gi = g * nchunk;
        digbase[g] = dm[gi] + bsum[gi >> 8];
    }
    if (tid == 0) digbase[NDIGIT] = n_edges;
}

// ---------------------------------------------------------------------------
// FUSED: blocks [0,nreb) = deterministic stable radix scatter (4 waves/block,
// one 1024-edge chunk per wave, wave-private LDS cnt -> no barriers needed);
// blocks [nreb,..) = MFMA projection (validated body, row0 shifted).
// The two roles are data-independent -> they co-schedule on the CUs and
// reorder's latency hides under gemm's MFMA/BW work.
// ---------------------------------------------------------------------------
__global__ __launch_bounds__(256) void reorder_gemm_kernel(
    const int* __restrict__ src, const int* __restrict__ dst,
    unsigned* __restrict__ P1, const int* __restrict__ dm,
    const int* __restrict__ bsum2,
    const float* __restrict__ h, const unsigned short* __restrict__ wt_g,
    const float* __restrict__ norm, unsigned short* __restrict__ hwn,
    int n_edges, int nchunk, int n_nodes, int nreb)
{
    __shared__ __align__(16) unsigned char lds[65536];
    const int tid = threadIdx.x;

    if ((int)blockIdx.x < nreb) {
        // ---- reorder: wave-private cnt in first 8 KB of lds ----
        const int wv = tid >> 6;
        const int c = blockIdx.x * 4 + wv;
        if (c >= nchunk) return;
        unsigned* cnt = reinterpret_cast<unsigned*>(lds) + wv * NDIGIT;
        const int lane = tid & 63;
        #pragma unroll
        for (int j = 0; j < NDIGIT / 64; ++j) cnt[lane + j * 64] = 0;
        // no barrier: cnt is wave-private; LDS ops are wave-ordered
        const int base = c * RCHUNK;

        unsigned dA = 0, sA = 0, dB = 0, sB = 0;
        if (base + lane < n_edges)      { dA = dst[base + lane];      sA = src[base + lane]; }
        if (base + 64 + lane < n_edges) { dB = dst[base + 64 + lane]; sB = src[base + 64 + lane]; }

        for (int r = 0; r < RROUNDS; ++r) {
            unsigned dC = 0, sC = 0;
            const int idxC = base + (r + 2) * 64 + lane;
            if (r + 2 < RROUNDS && idxC < n_edges) { dC = dst[idxC]; sC = src[idxC]; }

            const int idx = base + r * 64 + lane;
            const bool valid = idx < n_edges;
            const int g = valid ? (int)(dA >> DSHIFT) : NDIGIT;
            unsigned long long m = ~0ull;
            #pragma unroll
            for (int b = 0; b < 10; ++b) {
                const unsigned long long bb = __ballot((g >> b) & 1);
                m &= ((g >> b) & 1) ? bb : ~bb;
            }
            const unsigned long long below = m & ((1ull << lane) - 1ull);
            const int laneRank = __popcll(below);
            const int total = __popcll(m);
            const bool isFirst = (below == 0ull);
            if (valid) {
                const unsigned oldc = cnt[g];
                const int gi = g * nchunk + c;
                const unsigned slot = (unsigned)dm[gi] + (unsigned)bsum2[gi >> 8]
                                    + oldc + (unsigned)laneRank;
                P1[slot] = ((dA & (unsigned)NMASK) << 16) | sA;
                if (isFirst) cnt[g] = oldc + (unsigned)total;
            }
            dA = dB; sA = sB; dB = dC; sB = sC;
        }
    } else {
        // ---- gemm (validated) ----
        const int row0 = ((int)blockIdx.x - nreb) * 64;

        #pragma unroll
        for (int j = 0; j < 8; ++j) {
            const int ch = j * 256 + tid;
            const int r = ch >> 5, k0 = (ch & 31) * 8;
            const int row = row0 + r;
            ushort8 v;
            if (row < n_nodes) {
                const float4 f0 = *reinterpret_cast<const float4*>(h + (size_t)row * K_FEATS + k0);
                const float4 f1 = *reinterpret_cast<const float4*>(h + (size_t)row * K_FEATS + k0 + 4);
                v[0]=f2bf(f0.x); v[1]=f2bf(f0.y); v[2]=f2bf(f0.z); v[3]=f2bf(f0.w);
                v[4]=f2bf(f1.x); v[5]=f2bf(f1.y); v[6]=f2bf(f1.z); v[7]=f2bf(f1.w);
            } else {
                v = (ushort8)0;
            }
            const int addr = (r * 512 + k0 * 2) ^ ((r & 7) << 4);
            *reinterpret_cast<ushort8*>(lds + addr) = v;
        }
        #pragma unroll
        for (int j = 0; j < 8; ++j) {
            const int ch = j * 256 + tid;
            const int col = ch >> 5, k0 = (ch & 31) * 8;
            const ushort8 v = *reinterpret_cast<const ushort8*>(wt_g + ch * 8);
            const int addr = 32768 + ((col * 512 + k0 * 2) ^ ((col & 7) << 4));
            *reinterpret_cast<ushort8*>(lds + addr) = v;
        }
        __syncthreads();

        const int lane = tid & 63, w = tid >> 6;
        const int r16 = lane & 15, kg = lane >> 4;
        const int x = (r16 & 7) << 4;

        f32x4 acc[4];
        #pragma unroll
        for (int n = 0; n < 4; ++n) acc[n] = (f32x4)0.f;

        #pragma unroll
        for (int kb = 0; kb < 8; ++kb) {
            const int common = (r16 * 512 + kb * 64 + kg * 16) ^ x;
            const short8 a = *reinterpret_cast<const short8*>(lds + w * 8192 + common);
            #pragma unroll
            for (int n = 0; n < 4; ++n) {
                const short8 b = *reinterpret_cast<const short8*>(lds + 32768 + n * 8192 + common);
                acc[n] = __builtin_amdgcn_mfma_f32_16x16x32_bf16(a, b, acc[n], 0, 0, 0);
            }
        }

        #pragma unroll
        for (int i = 0; i < 4; ++i) {
            const int row = row0 + w * 16 + kg * 4 + i;
            if (row < n_nodes) {
                const float nv = norm[row];
                #pragma unroll
                for (int n = 0; n < 4; ++n) {
                    hwn[(size_t)row * C_FEATS + n * 16 + r16] = f2bf(acc[n][i] * nv);
                }
            }
        }
    }
}

// ---------------------------------------------------------------------------
// Aggregate + finalize (validated round 11). Block = 128-node bucket,
// 512 threads; local segment build; 8-edge-parallel uint4 gather.
// ---------------------------------------------------------------------------
__global__ __launch_bounds__(512) void aggregate_kernel(
    const uint4* __restrict__ hwn4, const unsigned* __restrict__ P1,
    const int* __restrict__ digbase,
    const float* __restrict__ norm, const float* __restrict__ bias,
    float* __restrict__ out, int n_nodes)
{
    __shared__ unsigned stage[LCAP];
    __shared__ unsigned short lsrc[LCAP];
    __shared__ int cnt128[128];
    __shared__ int cur128[128];
    __shared__ int segbase[129];

    const int tid = threadIdx.x;
    const int b = blockIdx.x;
    const int n0 = b * 128;

    const int s = digbase[b];
    const int bucketsz = digbase[b + 1] - s;

    if (tid < 128) { cnt128[tid] = 0; cur128[tid] = 0; }
    __syncthreads();

    const int lane = tid & 63;
    const int wv = tid >> 6;           // 8 waves
    const int q  = lane >> 3;          // edge slot 0..7
    const int c8 = lane & 7;           // uint4 index within 128B row

    if (bucketsz <= LCAP) {
        for (int i = tid; i < bucketsz; i += 512) {
            const unsigned key = P1[s + i];
            stage[i] = key;
            atomicAdd(&cnt128[key >> 16], 1);
        }
        __syncthreads();
        if (tid < 64) {
            const int a = cnt128[2 * tid], bb = cnt128[2 * tid + 1];
            int p = a + bb;
            #pragma unroll
            for (int d = 1; d < 64; d <<= 1) {
                const int t = __shfl_up(p, d);
                if (tid >= d) p += t;
            }
            segbase[2 * tid]     = p - a - bb;
            segbase[2 * tid + 1] = p - bb;
            if (tid == 63) segbase[128] = p;
        }
        __syncthreads();
        for (int i = tid; i < bucketsz; i += 512) {
            const unsigned key = stage[i];
            const int nn = key >> 16;
            const int pos = atomicAdd(&cur128[nn], 1);
            lsrc[segbase[nn] + pos] = (unsigned short)key;
        }
        __syncthreads();
        for (int nn = wv; nn < 128; nn += 8) {
            const int node = n0 + nn;
            if (node >= n_nodes) break;
            const int ls = segbase[nn];
            const int le = segbase[nn + 1];
            float a0=0.f,a1=0.f,a2=0.f,a3=0.f,a4=0.f,a5=0.f,a6=0.f,a7=0.f;
            int e = ls + q;
            for (; e + 8 < le; e += 16) {
                const uint4 u = hwn4[(size_t)lsrc[e] * 8 + c8];
                const uint4 v = hwn4[(size_t)lsrc[e + 8] * 8 + c8];
                a0 += bflo(u.x) + bflo(v.x); a1 += bfhi(u.x) + bfhi(v.x);
                a2 += bflo(u.y) + bflo(v.y); a3 += bfhi(u.y) + bfhi(v.y);
                a4 += bflo(u.z) + bflo(v.z); a5 += bfhi(u.z) + bfhi(v.z);
                a6 += bflo(u.w) + bflo(v.w); a7 += bfhi(u.w) + bfhi(v.w);
            }
            for (; e < le; e += 8) {
                const uint4 u = hwn4[(size_t)lsrc[e] * 8 + c8];
                a0 += bflo(u.x); a1 += bfhi(u.x);
                a2 += bflo(u.y); a3 += bfhi(u.y);
                a4 += bflo(u.z); a5 += bfhi(u.z);
                a6 += bflo(u.w); a7 += bfhi(u.w);
            }
            #pragma unroll
            for (int d = 8; d < 64; d <<= 1) {
                a0 += __shfl_xor(a0, d); a1 += __shfl_xor(a1, d);
                a2 += __shfl_xor(a2, d); a3 += __shfl_xor(a3, d);
                a4 += __shfl_xor(a4, d); a5 += __shfl_xor(a5, d);
                a6 += __shfl_xor(a6, d); a7 += __shfl_xor(a7, d);
            }
            if (q == 0) {
                const float nv = norm[node];
                const float4 b0 = *reinterpret_cast<const float4*>(bias + c8 * 8);
                const float4 b1 = *reinterpret_cast<const float4*>(bias + c8 * 8 + 4);
                float4 o0, o1;
                o0.x = fmaxf(fmaf(a0, nv, b0.x), 0.f);
                o0.y = fmaxf(fmaf(a1, nv, b0.y), 0.f);
                o0.z = fmaxf(fmaf(a2, nv, b0.z), 0.f);
                o0.w = fmaxf(fmaf(a3, nv, b0.w), 0.f);
                o1.x = fmaxf(fmaf(a4, nv, b1.x), 0.f);
                o1.y = fmaxf(fmaf(a5, nv, b1.y), 0.f);
                o1.z = fmaxf(fmaf(a6, nv, b1.z), 0.f);
                o1.w = fmaxf(fmaf(a7, nv, b1.w), 0.f);
                float* po = out + (size_t)node * C_FEATS + c8 * 8;
                *reinterpret_cast<float4*>(po)     = o0;
                *reinterpret_cast<float4*>(po + 4) = o1;
            }
        }
    } else {
        for (int nn = wv; nn < 128; nn += 8) {
            const int node = n0 + nn;
            if (node >= n_nodes) break;
            float a0=0.f,a1=0.f,a2=0.f,a3=0.f,a4=0.f,a5=0.f,a6=0.f,a7=0.f;
            for (int i = q; i < bucketsz; i += 8) {
                const unsigned key = P1[s + i];
                if ((int)(key >> 16) == nn) {
                    const uint4 u = hwn4[(size_t)(key & 0xFFFFu) * 8 + c8];
                    a0 += bflo(u.x); a1 += bfhi(u.x);
                    a2 += bflo(u.y); a3 += bfhi(u.y);
                    a4 += bflo(u.z); a5 += bfhi(u.z);
                    a6 += bflo(u.w); a7 += bfhi(u.w);
                }
            }
            #pragma unroll
            for (int d = 8; d < 64; d <<= 1) {
                a0 += __shfl_xor(a0, d); a1 += __shfl_xor(a1, d);
                a2 += __shfl_xor(a2, d); a3 += __shfl_xor(a3, d);
                a4 += __shfl_xor(a4, d); a5 += __shfl_xor(a5, d);
                a6 += __shfl_xor(a6, d); a7 += __shfl_xor(a7, d);
            }
            if (q == 0) {
                const float nv = norm[node];
                const float4 b0 = *reinterpret_cast<const float4*>(bias + c8 * 8);
                const float4 b1 = *reinterpret_cast<const float4*>(bias + c8 * 8 + 4);
                float4 o0, o1;
                o0.x = fmaxf(fmaf(a0, nv, b0.x), 0.f);
                o0.y = fmaxf(fmaf(a1, nv, b0.y), 0.f);
                o0.z = fmaxf(fmaf(a2, nv, b0.z), 0.f);
                o0.w = fmaxf(fmaf(a3, nv, b0.w), 0.f);
                o1.x = fmaxf(fmaf(a4, nv, b1.x), 0.f);
                o1.y = fmaxf(fmaf(a5, nv, b1.y), 0.f);
                o1.z = fmaxf(fmaf(a6, nv, b1.z), 0.f);
                o1.w = fmaxf(fmaf(a7, nv, b1.w), 0.f);
                float* po = out + (size_t)node * C_FEATS + c8 * 8;
                *reinterpret_cast<float4*>(po)     = o0;
                *reinterpret_cast<float4*>(po + 4) = o1;
            }
        }
    }
}

extern "C" void kernel_launch(void* const* d_in, const int* in_sizes, int n_in,
                              void* d_out, int out_size, void* d_ws, size_t ws_size,
                              hipStream_t stream) {
    const float* h      = (const float*)d_in[0];
    const float* norm   = (const float*)d_in[1];
    const int*   src    = (const int*)d_in[2];
    const int*   dst    = (const int*)d_in[3];
    const float* weight = (const float*)d_in[4];
    const float* bias   = (const float*)d_in[5];

    const int n_nodes = in_sizes[1];
    const int n_edges = in_sizes[2];

    char* ws = (char*)d_ws;
    unsigned* P1            = (unsigned*)(ws + 0);
    int* dm                 = (int*)(ws + 3200000);
    unsigned short* cm16    = (unsigned short*)(ws + 4801536);
    unsigned short* hwn     = (unsigned short*)(ws + 5602304);
    int* bsum2              = (int*)(ws + 12002304);
    int* digbase            = (int*)(ws + 12008560);
    unsigned short* wt_g    = (unsigned short*)(ws + 12010624);

    const int nchunk  = (n_edges + RCHUNK - 1) / RCHUNK;          // 782
    const int nscan   = NDIGIT * nchunk;                          // 400384
    const int nb_r    = (nscan + 255) / 256;                      // 1564 <= 4096
    const int ngroup  = (n_nodes + 127) / 128;                    // 391
    const int nreb    = (nchunk + 3) / 4;                         // 196
    const int ngemm   = (n_nodes + 63) / 64;                      // 782

    // 1) fused digit histogram (u16 chunk-major) + W transpose
    packhist_w_kernel<<<nchunk + 16, 256, 0, stream>>>(dst, cm16, weight, wt_g,
                                                       n_edges, nchunk);
    // 2) digit-major block scan (reads cm16 transposed)
    scan_block_t_kernel<<<nb_r, 256, 0, stream>>>(cm16, dm, bsum2, nscan, nchunk);
    // 3) partials scan + digbase snapshot
    scan_partials_digbase_kernel<<<1, 256, 0, stream>>>(bsum2, nb_r, dm, digbase,
                                                        n_edges, nchunk);
    // 4) FUSED reorder (196 blocks) + gemm (782 blocks) — concurrent
    reorder_gemm_kernel<<<nreb + ngemm, 256, 0, stream>>>(
        src, dst, P1, dm, bsum2, h, wt_g, norm, hwn,
        n_edges, nchunk, n_nodes, nreb);
    // 5) bucket-local split + gather-aggregate + finalize
    aggregate_kernel<<<ngroup, 512, 0, stream>>>(
        (const uint4*)hwn, P1, digbase, norm, bias, (float*)d_out, n_nodes);
}

// Round 13
// 70.302 us; speedup vs baseline: 1.8166x; 1.0456x over previous
//
#include <hip/hip_runtime.h>

#define K_FEATS 256
#define C_FEATS 64
#define RCHUNK 1024
#define RROUNDS (RCHUNK / 64)
#define NDIGIT 512           // digit = dst>>7, dst<65536 -> digit<512
#define DSHIFT 7
#define NMASK 127
#define LCAP 2560            // per-bucket LDS edge capacity (avg 2048)

typedef __attribute__((ext_vector_type(8))) short short8;
typedef __attribute__((ext_vector_type(8))) unsigned short ushort8;
typedef __attribute__((ext_vector_type(4))) float f32x4;

__device__ __forceinline__ unsigned short f2bf(float f) {
    union { float f; unsigned u; } v; v.f = f;
    unsigned r = v.u + 0x7FFF + ((v.u >> 16) & 1);   // RNE, finite inputs
    return (unsigned short)(r >> 16);
}

__device__ __forceinline__ float bflo(unsigned u) { return __uint_as_float(u << 16); }
__device__ __forceinline__ float bfhi(unsigned u) { return __uint_as_float(u & 0xFFFF0000u); }

// ---------------------------------------------------------------------------
// ws layout (bytes) — every GLOBAL buffer is a pure function of the inputs.
// nchunk = 782.
//   P1 (uint)   : 0          ..  3,200,000   (dst&127)<<16|src, sorted by dst>>7
//   dm (int)    : 3,200,000  ..  4,801,536   [digit][chunk] within-bucket
//                                            exclusive chunk offsets
//   cm16 (u16)  : 4,801,536  ..  5,602,304   [chunk][512 digits] coalesced
//   hwn (bf16)  : 5,602,304  .. 12,002,304
//   totals(int) : 12,002,304 .. 12,004,352   per-digit bucket sizes
//   wt_g (bf16) : 12,004,352 .. 12,037,120   W^T bf16 (16B aligned)
// total ~12.04 MB
// ---------------------------------------------------------------------------

// fused: per-chunk 512-bin digit histogram (u16 chunk-major, coalesced)
// [blocks 0..nchunk) + W transpose to bf16 [blocks nchunk..nchunk+16)
__global__ __launch_bounds__(256) void packhist_w_kernel(
    const int* __restrict__ dst, unsigned short* __restrict__ cm16,
    const float* __restrict__ w, unsigned short* __restrict__ wt,
    int n_edges, int nchunk)
{
    const int tid = threadIdx.x;
    if ((int)blockIdx.x < nchunk) {
        __shared__ unsigned cnt[NDIGIT];
        #pragma unroll
        for (int j = 0; j < NDIGIT / 256; ++j) cnt[tid + j * 256] = 0;
        __syncthreads();
        const int e0 = blockIdx.x * RCHUNK + tid * 4;
        if (e0 + 3 < n_edges) {
            const int4 d4 = *reinterpret_cast<const int4*>(dst + e0);
            atomicAdd(&cnt[d4.x >> DSHIFT], 1);
            atomicAdd(&cnt[d4.y >> DSHIFT], 1);
            atomicAdd(&cnt[d4.z >> DSHIFT], 1);
            atomicAdd(&cnt[d4.w >> DSHIFT], 1);
        } else {
            #pragma unroll
            for (int j = 0; j < 4; ++j) {
                if (e0 + j < n_edges) atomicAdd(&cnt[dst[e0 + j] >> DSHIFT], 1);
            }
        }
        __syncthreads();
        const unsigned o = cnt[tid * 2] | (cnt[tid * 2 + 1] << 16);
        reinterpret_cast<unsigned*>(cm16)[(size_t)blockIdx.x * (NDIGIT / 2) + tid] = o;
    } else {
        const int e2 = ((int)blockIdx.x - nchunk) * 1024 + tid;
        #pragma unroll
        for (int j = 0; j < 4; ++j) {
            const int idx = e2 + j * 256;           // linear in wt [col][k]
            const int col = idx >> 8, k = idx & 255;
            wt[idx] = f2bf(w[k * C_FEATS + col]);
        }
    }
}

// one block per digit: exclusive scan of its 782 chunk counts (-> dm row,
// within-bucket offsets) + bucket total. Thread t owns chunks 4t..4t+3.
__global__ __launch_bounds__(256) void bucketscan_kernel(
    const unsigned short* __restrict__ cm16, int* __restrict__ dm,
    int* __restrict__ totals, int nchunk)
{
    __shared__ int s[256];
    const int g = blockIdx.x;
    const int t = threadIdx.x;
    int v[4];
    int sum = 0;
    #pragma unroll
    for (int j = 0; j < 4; ++j) {
        const int c = t * 4 + j;
        v[j] = (c < nchunk) ? (int)cm16[(size_t)c * NDIGIT + g] : 0;
        sum += v[j];
    }
    s[t] = sum;
    __syncthreads();
    #pragma unroll
    for (int d = 1; d < 256; d <<= 1) {
        int x = (t >= d) ? s[t - d] : 0;
        __syncthreads();
        s[t] += x;
        __syncthreads();
    }
    int base = s[t] - sum;
    #pragma unroll
    for (int j = 0; j < 4; ++j) {
        const int c = t * 4 + j;
        if (c < nchunk) dm[(size_t)g * nchunk + c] = base;
        base += v[j];
    }
    if (t == 255) totals[g] = s[255];
}

// ---------------------------------------------------------------------------
// FUSED: blocks [0,nreb) = deterministic stable radix scatter (4 waves/block,
// one 1024-edge chunk per wave, wave-private LDS cnt); blocks [nreb,..) =
// MFMA projection. Reorder blocks first redundantly scan totals -> digbaseL.
// ---------------------------------------------------------------------------
__global__ __launch_bounds__(256) void reorder_gemm_kernel(
    const int* __restrict__ src, const int* __restrict__ dst,
    unsigned* __restrict__ P1, const int* __restrict__ dm,
    const int* __restrict__ totals,
    const float* __restrict__ h, const unsigned short* __restrict__ wt_g,
    const float* __restrict__ norm, unsigned short* __restrict__ hwn,
    int n_edges, int nchunk, int n_nodes, int nreb)
{
    __shared__ __align__(16) unsigned char lds[65536];
    const int tid = threadIdx.x;

    if ((int)blockIdx.x < nreb) {
        unsigned* cntall  = reinterpret_cast<unsigned*>(lds);        // 4*512*4 = 8KB
        int* ss           = reinterpret_cast<int*>(lds + 8192);      // 1KB
        int* digbaseL     = reinterpret_cast<int*>(lds + 9216);      // 2KB
        // exclusive scan of totals (512 entries, 2 per thread)
        {
            const int a  = totals[2 * tid];
            const int b2 = totals[2 * tid + 1];
            ss[tid] = a + b2;
            __syncthreads();
            #pragma unroll
            for (int d = 1; d < 256; d <<= 1) {
                int x = (tid >= d) ? ss[tid - d] : 0;
                __syncthreads();
                ss[tid] += x;
                __syncthreads();
            }
            const int base = ss[tid] - (a + b2);
            digbaseL[2 * tid]     = base;
            digbaseL[2 * tid + 1] = base + a;
            __syncthreads();
        }
        const int wv = tid >> 6;
        const int c = blockIdx.x * 4 + wv;
        if (c >= nchunk) return;
        unsigned* cnt = cntall + wv * NDIGIT;
        const int lane = tid & 63;
        #pragma unroll
        for (int j = 0; j < NDIGIT / 64; ++j) cnt[lane + j * 64] = 0;
        // no barrier: cnt is wave-private; LDS ops are wave-ordered
        const int base = c * RCHUNK;

        unsigned dA = 0, sA = 0, dB = 0, sB = 0;
        if (base + lane < n_edges)      { dA = dst[base + lane];      sA = src[base + lane]; }
        if (base + 64 + lane < n_edges) { dB = dst[base + 64 + lane]; sB = src[base + 64 + lane]; }

        for (int r = 0; r < RROUNDS; ++r) {
            unsigned dC = 0, sC = 0;
            const int idxC = base + (r + 2) * 64 + lane;
            if (r + 2 < RROUNDS && idxC < n_edges) { dC = dst[idxC]; sC = src[idxC]; }

            const int idx = base + r * 64 + lane;
            const bool valid = idx < n_edges;
            const int g = valid ? (int)(dA >> DSHIFT) : NDIGIT;
            unsigned long long m = ~0ull;
            #pragma unroll
            for (int b = 0; b < 10; ++b) {
                const unsigned long long bb = __ballot((g >> b) & 1);
                m &= ((g >> b) & 1) ? bb : ~bb;
            }
            const unsigned long long below = m & ((1ull << lane) - 1ull);
            const int laneRank = __popcll(below);
            const int total = __popcll(m);
            const bool isFirst = (below == 0ull);
            if (valid) {
                const unsigned oldc = cnt[g];
                const unsigned slot = (unsigned)digbaseL[g]
                                    + (unsigned)dm[(size_t)g * nchunk + c]
                                    + oldc + (unsigned)laneRank;
                P1[slot] = ((dA & (unsigned)NMASK) << 16) | sA;
                if (isFirst) cnt[g] = oldc + (unsigned)total;
            }
            dA = dB; sA = sB; dB = dC; sB = sC;
        }
    } else {
        // ---- gemm (validated) ----
        const int row0 = ((int)blockIdx.x - nreb) * 64;

        #pragma unroll
        for (int j = 0; j < 8; ++j) {
            const int ch = j * 256 + tid;
            const int r = ch >> 5, k0 = (ch & 31) * 8;
            const int row = row0 + r;
            ushort8 v;
            if (row < n_nodes) {
                const float4 f0 = *reinterpret_cast<const float4*>(h + (size_t)row * K_FEATS + k0);
                const float4 f1 = *reinterpret_cast<const float4*>(h + (size_t)row * K_FEATS + k0 + 4);
                v[0]=f2bf(f0.x); v[1]=f2bf(f0.y); v[2]=f2bf(f0.z); v[3]=f2bf(f0.w);
                v[4]=f2bf(f1.x); v[5]=f2bf(f1.y); v[6]=f2bf(f1.z); v[7]=f2bf(f1.w);
            } else {
                v = (ushort8)0;
            }
            const int addr = (r * 512 + k0 * 2) ^ ((r & 7) << 4);
            *reinterpret_cast<ushort8*>(lds + addr) = v;
        }
        #pragma unroll
        for (int j = 0; j < 8; ++j) {
            const int ch = j * 256 + tid;
            const int col = ch >> 5, k0 = (ch & 31) * 8;
            const ushort8 v = *reinterpret_cast<const ushort8*>(wt_g + ch * 8);
            const int addr = 32768 + ((col * 512 + k0 * 2) ^ ((col & 7) << 4));
            *reinterpret_cast<ushort8*>(lds + addr) = v;
        }
        __syncthreads();

        const int lane = tid & 63, w = tid >> 6;
        const int r16 = lane & 15, kg = lane >> 4;
        const int x = (r16 & 7) << 4;

        f32x4 acc[4];
        #pragma unroll
        for (int n = 0; n < 4; ++n) acc[n] = (f32x4)0.f;

        #pragma unroll
        for (int kb = 0; kb < 8; ++kb) {
            const int common = (r16 * 512 + kb * 64 + kg * 16) ^ x;
            const short8 a = *reinterpret_cast<const short8*>(lds + w * 8192 + common);
            #pragma unroll
            for (int n = 0; n < 4; ++n) {
                const short8 b = *reinterpret_cast<const short8*>(lds + 32768 + n * 8192 + common);
                acc[n] = __builtin_amdgcn_mfma_f32_16x16x32_bf16(a, b, acc[n], 0, 0, 0);
            }
        }

        #pragma unroll
        for (int i = 0; i < 4; ++i) {
            const int row = row0 + w * 16 + kg * 4 + i;
            if (row < n_nodes) {
                const float nv = norm[row];
                #pragma unroll
                for (int n = 0; n < 4; ++n) {
                    hwn[(size_t)row * C_FEATS + n * 16 + r16] = f2bf(acc[n][i] * nv);
                }
            }
        }
    }
}

// ---------------------------------------------------------------------------
// Aggregate + finalize (validated round 11/12 body). Block = 128-node bucket,
// 512 threads. Bucket bounds via redundant LDS scan of totals.
// ---------------------------------------------------------------------------
__global__ __launch_bounds__(512) void aggregate_kernel(
    const uint4* __restrict__ hwn4, const unsigned* __restrict__ P1,
    const int* __restrict__ totals,
    const float* __restrict__ norm, const float* __restrict__ bias,
    float* __restrict__ out, int n_nodes, int n_edges)
{
    __shared__ unsigned stage[LCAP];
    __shared__ unsigned short lsrc[LCAP];
    __shared__ int cnt128[128];
    __shared__ int cur128[128];
    __shared__ int segbase[129];
    __shared__ int ds[NDIGIT];

    const int tid = threadIdx.x;
    const int b = blockIdx.x;
    const int n0 = b * 128;

    // exclusive scan of totals (512 entries, 1 per thread)
    const int v = totals[tid];
    ds[tid] = v;
    __syncthreads();
    #pragma unroll
    for (int d = 1; d < NDIGIT; d <<= 1) {
        int x = (tid >= d) ? ds[tid - d] : 0;
        __syncthreads();
        ds[tid] += x;
        __syncthreads();
    }
    const int incl = ds[tid];
    __syncthreads();
    ds[tid] = incl - v;     // exclusive
    if (tid < 128) { cnt128[tid] = 0; cur128[tid] = 0; }
    __syncthreads();

    const int s = ds[b];
    const int bucketsz = ((b + 1 < NDIGIT) ? ds[b + 1] : n_edges) - s;

    const int lane = tid & 63;
    const int wv = tid >> 6;           // 8 waves
    const int q  = lane >> 3;          // edge slot 0..7
    const int c8 = lane & 7;           // uint4 index within 128B row

    if (bucketsz <= LCAP) {
        for (int i = tid; i < bucketsz; i += 512) {
            const unsigned key = P1[s + i];
            stage[i] = key;
            atomicAdd(&cnt128[key >> 16], 1);
        }
        __syncthreads();
        if (tid < 64) {
            const int a = cnt128[2 * tid], bb = cnt128[2 * tid + 1];
            int p = a + bb;
            #pragma unroll
            for (int d = 1; d < 64; d <<= 1) {
                const int t = __shfl_up(p, d);
                if (tid >= d) p += t;
            }
            segbase[2 * tid]     = p - a - bb;
            segbase[2 * tid + 1] = p - bb;
            if (tid == 63) segbase[128] = p;
        }
        __syncthreads();
        for (int i = tid; i < bucketsz; i += 512) {
            const unsigned key = stage[i];
            const int nn = key >> 16;
            const int pos = atomicAdd(&cur128[nn], 1);
            lsrc[segbase[nn] + pos] = (unsigned short)key;
        }
        __syncthreads();
        for (int nn = wv; nn < 128; nn += 8) {
            const int node = n0 + nn;
            if (node >= n_nodes) break;
            const int ls = segbase[nn];
            const int le = segbase[nn + 1];
            float a0=0.f,a1=0.f,a2=0.f,a3=0.f,a4=0.f,a5=0.f,a6=0.f,a7=0.f;
            int e = ls + q;
            for (; e + 8 < le; e += 16) {
                const uint4 u = hwn4[(size_t)lsrc[e] * 8 + c8];
                const uint4 w2 = hwn4[(size_t)lsrc[e + 8] * 8 + c8];
                a0 += bflo(u.x) + bflo(w2.x); a1 += bfhi(u.x) + bfhi(w2.x);
                a2 += bflo(u.y) + bflo(w2.y); a3 += bfhi(u.y) + bfhi(w2.y);
                a4 += bflo(u.z) + bflo(w2.z); a5 += bfhi(u.z) + bfhi(w2.z);
                a6 += bflo(u.w) + bflo(w2.w); a7 += bfhi(u.w) + bfhi(w2.w);
            }
            for (; e < le; e += 8) {
                const uint4 u = hwn4[(size_t)lsrc[e] * 8 + c8];
                a0 += bflo(u.x); a1 += bfhi(u.x);
                a2 += bflo(u.y); a3 += bfhi(u.y);
                a4 += bflo(u.z); a5 += bfhi(u.z);
                a6 += bflo(u.w); a7 += bfhi(u.w);
            }
            #pragma unroll
            for (int d = 8; d < 64; d <<= 1) {
                a0 += __shfl_xor(a0, d); a1 += __shfl_xor(a1, d);
                a2 += __shfl_xor(a2, d); a3 += __shfl_xor(a3, d);
                a4 += __shfl_xor(a4, d); a5 += __shfl_xor(a5, d);
                a6 += __shfl_xor(a6, d); a7 += __shfl_xor(a7, d);
            }
            if (q == 0) {
                const float nv = norm[node];
                const float4 b0 = *reinterpret_cast<const float4*>(bias + c8 * 8);
                const float4 b1 = *reinterpret_cast<const float4*>(bias + c8 * 8 + 4);
                float4 o0, o1;
                o0.x = fmaxf(fmaf(a0, nv, b0.x), 0.f);
                o0.y = fmaxf(fmaf(a1, nv, b0.y), 0.f);
                o0.z = fmaxf(fmaf(a2, nv, b0.z), 0.f);
                o0.w = fmaxf(fmaf(a3, nv, b0.w), 0.f);
                o1.x = fmaxf(fmaf(a4, nv, b1.x), 0.f);
                o1.y = fmaxf(fmaf(a5, nv, b1.y), 0.f);
                o1.z = fmaxf(fmaf(a6, nv, b1.z), 0.f);
                o1.w = fmaxf(fmaf(a7, nv, b1.w), 0.f);
                float* po = out + (size_t)node * C_FEATS + c8 * 8;
                *reinterpret_cast<float4*>(po)     = o0;
                *reinterpret_cast<float4*>(po + 4) = o1;
            }
        }
    } else {
        // safe fallback for oversized buckets (never expected on this input)
        for (int nn = wv; nn < 128; nn += 8) {
            const int node = n0 + nn;
            if (node >= n_nodes) break;
            float a0=0.f,a1=0.f,a2=0.f,a3=0.f,a4=0.f,a5=0.f,a6=0.f,a7=0.f;
            for (int i = q; i < bucketsz; i += 8) {
                const unsigned key = P1[s + i];
                if ((int)(key >> 16) == nn) {
                    const uint4 u = hwn4[(size_t)(key & 0xFFFFu) * 8 + c8];
                    a0 += bflo(u.x); a1 += bfhi(u.x);
                    a2 += bflo(u.y); a3 += bfhi(u.y);
                    a4 += bflo(u.z); a5 += bfhi(u.z);
                    a6 += bflo(u.w); a7 += bfhi(u.w);
                }
            }
            #pragma unroll
            for (int d = 8; d < 64; d <<= 1) {
                a0 += __shfl_xor(a0, d); a1 += __shfl_xor(a1, d);
                a2 += __shfl_xor(a2, d); a3 += __shfl_xor(a3, d);
                a4 += __shfl_xor(a4, d); a5 += __shfl_xor(a5, d);
                a6 += __shfl_xor(a6, d); a7 += __shfl_xor(a7, d);
            }
            if (q == 0) {
                const float nv = norm[node];
                const float4 b0 = *reinterpret_cast<const float4*>(bias + c8 * 8);
                const float4 b1 = *reinterpret_cast<const float4*>(bias + c8 * 8 + 4);
                float4 o0, o1;
                o0.x = fmaxf(fmaf(a0, nv, b0.x), 0.f);
                o0.y = fmaxf(fmaf(a1, nv, b0.y), 0.f);
                o0.z = fmaxf(fmaf(a2, nv, b0.z), 0.f);
                o0.w = fmaxf(fmaf(a3, nv, b0.w), 0.f);
                o1.x = fmaxf(fmaf(a4, nv, b1.x), 0.f);
                o1.y = fmaxf(fmaf(a5, nv, b1.y), 0.f);
                o1.z = fmaxf(fmaf(a6, nv, b1.z), 0.f);
                o1.w = fmaxf(fmaf(a7, nv, b1.w), 0.f);
                float* po = out + (size_t)node * C_FEATS + c8 * 8;
                *reinterpret_cast<float4*>(po)     = o0;
                *reinterpret_cast<float4*>(po + 4) = o1;
            }
        }
    }
}

extern "C" void kernel_launch(void* const* d_in, const int* in_sizes, int n_in,
                              void* d_out, int out_size, void* d_ws, size_t ws_size,
                              hipStream_t stream) {
    const float* h      = (const float*)d_in[0];
    const float* norm   = (const float*)d_in[1];
    const int*   src    = (const int*)d_in[2];
    const int*   dst    = (const int*)d_in[3];
    const float* weight = (const float*)d_in[4];
    const float* bias   = (const float*)d_in[5];

    const int n_nodes = in_sizes[1];
    const int n_edges = in_sizes[2];

    char* ws = (char*)d_ws;
    unsigned* P1            = (unsigned*)(ws + 0);
    int* dm                 = (int*)(ws + 3200000);
    unsigned short* cm16    = (unsigned short*)(ws + 4801536);
    unsigned short* hwn     = (unsigned short*)(ws + 5602304);
    int* totals             = (int*)(ws + 12002304);
    unsigned short* wt_g    = (unsigned short*)(ws + 12004352);

    const int nchunk  = (n_edges + RCHUNK - 1) / RCHUNK;          // 782
    const int ngroup  = (n_nodes + 127) / 128;                    // 391
    const int nreb    = (nchunk + 3) / 4;                         // 196
    const int ngemm   = (n_nodes + 63) / 64;                      // 782

    // 1) fused digit histogram (u16 chunk-major) + W transpose
    packhist_w_kernel<<<nchunk + 16, 256, 0, stream>>>(dst, cm16, weight, wt_g,
                                                       n_edges, nchunk);
    // 2) per-bucket scan of chunk counts -> dm (within-bucket) + totals
    bucketscan_kernel<<<NDIGIT, 256, 0, stream>>>(cm16, dm, totals, nchunk);
    // 3) FUSED reorder (196 blocks) + gemm (782 blocks) — concurrent
    reorder_gemm_kernel<<<nreb + ngemm, 256, 0, stream>>>(
        src, dst, P1, dm, totals, h, wt_g, norm, hwn,
        n_edges, nchunk, n_nodes, nreb);
    // 4) bucket-local split + gather-aggregate + finalize
    aggregate_kernel<<<ngroup, 512, 0, stream>>>(
        (const uint4*)hwn, P1, totals, norm, bias, (float*)d_out, n_nodes, n_edges);
}